// Round 1
// baseline (1391.970 us; speedup 1.0000x reference)
//
#include <hip/hip_runtime.h>
#include <hip/hip_bf16.h>

// Graph net: 4x (agg = A@h + h; h = tanh((agg@W + b)/deg1)); concat -> graph sum-pool -> relu(linear)
// N=100000 nodes, E=3200000 edges, G=64 graphs, feats 32, latent [32,32,32,1], out 128.
//
// Strategy: build CSR (edges grouped by dst) once per launch, then pull-style
// aggregation (no float atomics). 32 lanes per node (lane = feature), MLP fused
// via __shfl broadcast, pooling fused via atomicAdd into [64 x 97].

#define NFEAT 32
#define TOTLAT 97
#define NGRAPH 64
#define OUTDIM 128
#define SCAN_SEG 512

__global__ void count_kernel(const int* __restrict__ dst, int* __restrict__ cnt, int E) {
    for (int e = blockIdx.x * blockDim.x + threadIdx.x; e < E; e += gridDim.x * blockDim.x)
        atomicAdd(&cnt[dst[e]], 1);
}

__global__ void scan_a(const int* __restrict__ cnt, int* __restrict__ blockSums, int N) {
    __shared__ int s[SCAN_SEG];
    int i = blockIdx.x * SCAN_SEG + threadIdx.x;
    s[threadIdx.x] = (i < N) ? cnt[i] : 0;
    __syncthreads();
    for (int d = SCAN_SEG / 2; d > 0; d >>= 1) {
        if (threadIdx.x < d) s[threadIdx.x] += s[threadIdx.x + d];
        __syncthreads();
    }
    if (threadIdx.x == 0) blockSums[blockIdx.x] = s[0];
}

__global__ void scan_b(const int* __restrict__ blockSums, int* __restrict__ blockOffs, int nblk) {
    if (threadIdx.x == 0 && blockIdx.x == 0) {
        int run = 0;
        for (int b = 0; b < nblk; ++b) {
            blockOffs[b] = run;
            run += blockSums[b];
        }
    }
}

__global__ void scan_c(const int* __restrict__ cnt, const int* __restrict__ blockOffs,
                       int* __restrict__ row_ptr, int* __restrict__ cursor,
                       float* __restrict__ inv_deg, int N) {
    __shared__ int s[SCAN_SEG];
    int i = blockIdx.x * SCAN_SEG + threadIdx.x;
    int v = (i < N) ? cnt[i] : 0;
    s[threadIdx.x] = v;
    __syncthreads();
    // Hillis-Steele inclusive scan
    for (int d = 1; d < SCAN_SEG; d <<= 1) {
        int t = 0;
        if ((int)threadIdx.x >= d) t = s[threadIdx.x - d];
        __syncthreads();
        if ((int)threadIdx.x >= d) s[threadIdx.x] += t;
        __syncthreads();
    }
    int incl = s[threadIdx.x];
    int off = blockOffs[blockIdx.x];
    if (i < N) {
        int excl = off + incl - v;
        row_ptr[i] = excl;
        cursor[i] = excl;
        inv_deg[i] = 1.0f / ((float)v + 1.0f);
        if (i == N - 1) row_ptr[N] = off + incl;
    }
}

__global__ void fill_kernel(const int* __restrict__ src, const int* __restrict__ dst,
                            int* __restrict__ cursor, int* __restrict__ col_idx, int E) {
    for (int e = blockIdx.x * blockDim.x + threadIdx.x; e < E; e += gridDim.x * blockDim.x) {
        int pos = atomicAdd(&cursor[dst[e]], 1);
        col_idx[pos] = src[e];
    }
}

// One node per 32-lane group; lane = feature. Gather-aggregate + fused MLP + fused pooling.
template <int OUT_COLS>
__global__ __launch_bounds__(256) void layer_kernel(
    const float* __restrict__ h_in, float* __restrict__ h_out,
    const float* __restrict__ W, const float* __restrict__ b,
    const int* __restrict__ row_ptr, const int* __restrict__ col_idx,
    const float* __restrict__ inv_deg, const int* __restrict__ graph_ids,
    float* __restrict__ pooled, int pool_col, int N)
{
    int t = blockIdx.x * blockDim.x + threadIdx.x;
    int n = t >> 5;
    int f = t & 31;
    if (n >= N) return;

    int beg = row_ptr[n];
    int end = row_ptr[n + 1];
    float acc = h_in[(size_t)n * NFEAT + f];  // the "+ h" self term

    int e = beg;
    for (; e + 4 <= end; e += 4) {
        int i0 = col_idx[e + 0];
        int i1 = col_idx[e + 1];
        int i2 = col_idx[e + 2];
        int i3 = col_idx[e + 3];
        acc += h_in[(size_t)i0 * NFEAT + f];
        acc += h_in[(size_t)i1 * NFEAT + f];
        acc += h_in[(size_t)i2 * NFEAT + f];
        acc += h_in[(size_t)i3 * NFEAT + f];
    }
    for (; e < end; ++e)
        acc += h_in[(size_t)col_idx[e] * NFEAT + f];

    float ideg = inv_deg[n];
    int g = graph_ids[n];

    if (OUT_COLS == NFEAT) {
        // out_j = tanh((sum_k acc_k * W[k][j] + b[j]) * ideg), lane f computes j=f
        float o = b[f];
#pragma unroll
        for (int k = 0; k < NFEAT; ++k)
            o += __shfl(acc, k, 32) * W[k * NFEAT + f];
        float v = tanhf(o * ideg);
        h_out[(size_t)n * NFEAT + f] = v;
        atomicAdd(&pooled[g * TOTLAT + pool_col + f], v);
    } else {
        // single output column: dot(acc, W[:,0]) via butterfly reduce in 32-lane group
        float p = acc * W[f];
#pragma unroll
        for (int m = 16; m >= 1; m >>= 1)
            p += __shfl_xor(p, m, 32);
        if (f == 0) {
            float v = tanhf((p + b[0]) * ideg);
            atomicAdd(&pooled[g * TOTLAT + pool_col], v);
        }
    }
}

__global__ void final_kernel(const float* __restrict__ pooled, const float* __restrict__ Wout,
                             const float* __restrict__ bout, float* __restrict__ out) {
    int g = blockIdx.x;    // 64
    int o = threadIdx.x;   // 128
    float s = bout[o];
#pragma unroll 4
    for (int k = 0; k < TOTLAT; ++k)
        s += pooled[g * TOTLAT + k] * Wout[k * OUTDIM + o];
    out[g * OUTDIM + o] = fmaxf(s, 0.0f);
}

extern "C" void kernel_launch(void* const* d_in, const int* in_sizes, int n_in,
                              void* d_out, int out_size, void* d_ws, size_t ws_size,
                              hipStream_t stream) {
    const float* node_feat = (const float*)d_in[0];
    const int*   src       = (const int*)d_in[1];
    const int*   dst       = (const int*)d_in[2];
    const int*   graph_ids = (const int*)d_in[3];
    // d_in[4] = num_graphs scalar (64, hard-coded)
    const float* W0 = (const float*)d_in[5];
    const float* b0 = (const float*)d_in[6];
    const float* W1 = (const float*)d_in[7];
    const float* b1 = (const float*)d_in[8];
    const float* W2 = (const float*)d_in[9];
    const float* b2 = (const float*)d_in[10];
    const float* W3 = (const float*)d_in[11];
    const float* b3 = (const float*)d_in[12];
    const float* Wout = (const float*)d_in[13];
    const float* bout = (const float*)d_in[14];
    float* out = (float*)d_out;

    const int N = in_sizes[0] / NFEAT;   // 100000
    const int E = in_sizes[1];           // 3200000

    // workspace carve-out
    char* ws = (char*)d_ws;
    size_t off = 0;
    auto carve = [&](size_t bytes) -> void* {
        void* p = ws + off;
        off = (off + bytes + 255) & ~(size_t)255;
        return p;
    };
    int*   cnt       = (int*)carve((size_t)(N + 1) * 4);
    int*   row_ptr   = (int*)carve((size_t)(N + 1) * 4);
    int*   cursor    = (int*)carve((size_t)N * 4);
    int*   col_idx   = (int*)carve((size_t)E * 4);
    float* inv_deg   = (float*)carve((size_t)N * 4);
    float* hA        = (float*)carve((size_t)N * NFEAT * 4);
    float* hB        = (float*)carve((size_t)N * NFEAT * 4);
    float* pooled    = (float*)carve((size_t)NGRAPH * TOTLAT * 4);
    int*   blockSums = (int*)carve(4096);
    int*   blockOffs = (int*)carve(4096);

    hipMemsetAsync(cnt, 0, (size_t)(N + 1) * 4, stream);
    hipMemsetAsync(pooled, 0, (size_t)NGRAPH * TOTLAT * 4, stream);

    const int EBLK = 2048;
    count_kernel<<<EBLK, 256, 0, stream>>>(dst, cnt, E);

    const int nblk = (N + SCAN_SEG - 1) / SCAN_SEG;
    scan_a<<<nblk, SCAN_SEG, 0, stream>>>(cnt, blockSums, N);
    scan_b<<<1, 64, 0, stream>>>(blockSums, blockOffs, nblk);
    scan_c<<<nblk, SCAN_SEG, 0, stream>>>(cnt, blockOffs, row_ptr, cursor, inv_deg, N);
    fill_kernel<<<EBLK, 256, 0, stream>>>(src, dst, cursor, col_idx, E);

    const int lblocks = (N * 32 + 255) / 256;
    layer_kernel<32><<<lblocks, 256, 0, stream>>>(node_feat, hA, W0, b0, row_ptr, col_idx,
                                                  inv_deg, graph_ids, pooled, 0, N);
    layer_kernel<32><<<lblocks, 256, 0, stream>>>(hA, hB, W1, b1, row_ptr, col_idx,
                                                  inv_deg, graph_ids, pooled, 32, N);
    layer_kernel<32><<<lblocks, 256, 0, stream>>>(hB, hA, W2, b2, row_ptr, col_idx,
                                                  inv_deg, graph_ids, pooled, 64, N);
    layer_kernel<1><<<lblocks, 256, 0, stream>>>(hA, nullptr, W3, b3, row_ptr, col_idx,
                                                 inv_deg, graph_ids, pooled, 96, N);

    final_kernel<<<NGRAPH, OUTDIM, 0, stream>>>(pooled, Wout, bout, out);
}

// Round 4
// 980.921 us; speedup vs baseline: 1.4190x; 1.4190x over previous
//
#include <hip/hip_runtime.h>
#include <hip/hip_bf16.h>

// Graph net: 4x (agg = A@h + h; h = tanh((agg@W + b)/deg1)); concat -> graph sum-pool -> relu(linear)
// N=100000 nodes, E=3200000 edges, G=64 graphs, feats 32, latent [32,32,32,1], out 128.
//
// R3 == R1 resubmit (R1/R2 hit infra failures, never measured).
// Design: 8 lanes/node x float4 gathers (8 rows / wave instr, 8 KB outstanding
// per wave vs 1 KB in R0), shfl-broadcast indices, width-8 shfl MLP,
// wave-reduced pooling atomics, int4 CSR build, parallel scan_b.

#define NFEAT 32
#define TOTLAT 97
#define NGRAPH 64
#define OUTDIM 128
#define SCAN_SEG 512

__global__ void count_kernel(const int* __restrict__ dst, int* __restrict__ cnt, int E) {
    int stride = gridDim.x * blockDim.x;
    int i = blockIdx.x * blockDim.x + threadIdx.x;
    const int4* d4 = (const int4*)dst;
    int n4 = E >> 2;
    for (int k = i; k < n4; k += stride) {
        int4 v = d4[k];
        atomicAdd(&cnt[v.x], 1);
        atomicAdd(&cnt[v.y], 1);
        atomicAdd(&cnt[v.z], 1);
        atomicAdd(&cnt[v.w], 1);
    }
    for (int e = (n4 << 2) + i; e < E; e += stride)
        atomicAdd(&cnt[dst[e]], 1);
}

__global__ void scan_a(const int* __restrict__ cnt, int* __restrict__ blockSums, int N) {
    __shared__ int s[SCAN_SEG];
    int i = blockIdx.x * SCAN_SEG + threadIdx.x;
    s[threadIdx.x] = (i < N) ? cnt[i] : 0;
    __syncthreads();
    for (int d = SCAN_SEG / 2; d > 0; d >>= 1) {
        if (threadIdx.x < d) s[threadIdx.x] += s[threadIdx.x + d];
        __syncthreads();
    }
    if (threadIdx.x == 0) blockSums[blockIdx.x] = s[0];
}

// parallel exclusive scan of per-block sums (nblk <= 512)
__global__ void scan_b(const int* __restrict__ blockSums, int* __restrict__ blockOffs, int nblk) {
    __shared__ int s[SCAN_SEG];
    int i = threadIdx.x;
    int v = (i < nblk) ? blockSums[i] : 0;
    s[i] = v;
    __syncthreads();
    for (int d = 1; d < SCAN_SEG; d <<= 1) {
        int t = 0;
        if (i >= d) t = s[i - d];
        __syncthreads();
        if (i >= d) s[i] += t;
        __syncthreads();
    }
    if (i < nblk) blockOffs[i] = s[i] - v;
}

__global__ void scan_c(const int* __restrict__ cnt, const int* __restrict__ blockOffs,
                       int* __restrict__ row_ptr, int* __restrict__ cursor,
                       float* __restrict__ inv_deg, int N) {
    __shared__ int s[SCAN_SEG];
    int i = blockIdx.x * SCAN_SEG + threadIdx.x;
    int v = (i < N) ? cnt[i] : 0;
    s[threadIdx.x] = v;
    __syncthreads();
    for (int d = 1; d < SCAN_SEG; d <<= 1) {
        int t = 0;
        if ((int)threadIdx.x >= d) t = s[threadIdx.x - d];
        __syncthreads();
        if ((int)threadIdx.x >= d) s[threadIdx.x] += t;
        __syncthreads();
    }
    int incl = s[threadIdx.x];
    int off = blockOffs[blockIdx.x];
    if (i < N) {
        int excl = off + incl - v;
        row_ptr[i] = excl;
        cursor[i] = excl;
        inv_deg[i] = 1.0f / ((float)v + 1.0f);
        if (i == N - 1) row_ptr[N] = off + incl;
    }
}

__global__ void fill_kernel(const int* __restrict__ src, const int* __restrict__ dst,
                            int* __restrict__ cursor, int* __restrict__ col_idx, int E) {
    int stride = gridDim.x * blockDim.x;
    int i = blockIdx.x * blockDim.x + threadIdx.x;
    const int4* s4 = (const int4*)src;
    const int4* d4 = (const int4*)dst;
    int n4 = E >> 2;
    for (int k = i; k < n4; k += stride) {
        int4 d = d4[k];
        int4 s = s4[k];
        col_idx[atomicAdd(&cursor[d.x], 1)] = s.x;
        col_idx[atomicAdd(&cursor[d.y], 1)] = s.y;
        col_idx[atomicAdd(&cursor[d.z], 1)] = s.z;
        col_idx[atomicAdd(&cursor[d.w], 1)] = s.w;
    }
    for (int e = (n4 << 2) + i; e < E; e += stride) {
        int pos = atomicAdd(&cursor[dst[e]], 1);
        col_idx[pos] = src[e];
    }
}

// 8 lanes per node, lane owns feature quad f0 = (t&7)*4. float4 gathers.
template <int OUT_COLS>
__global__ __launch_bounds__(256) void layer_kernel(
    const float* __restrict__ h_in, float* __restrict__ h_out,
    const float* __restrict__ W, const float* __restrict__ b,
    const int* __restrict__ row_ptr, const int* __restrict__ col_idx,
    const float* __restrict__ inv_deg, const int* __restrict__ graph_ids,
    float* __restrict__ pooled, int pool_col, int N)
{
    const int t = blockIdx.x * blockDim.x + threadIdx.x;
    int n = t >> 3;
    const int l8 = t & 7;
    const int f0 = l8 * 4;
    const int lane = threadIdx.x & 63;
    const bool valid = n < N;
    if (!valid) n = N - 1;   // keep wave fully active for shfl/__all

    const float4* __restrict__ h4 = (const float4*)h_in;

    int beg = row_ptr[n];
    int end = row_ptr[n + 1];
    float4 acc = h4[(size_t)n * 8 + l8];   // self term

    int len = end - beg;
    int nfull = beg + (len & ~7);
    int e = beg;
    for (; e < nfull; e += 8) {
        int my = col_idx[e + l8];          // one coalesced idx load per chunk
#pragma unroll
        for (int j = 0; j < 8; ++j) {
            int idx = __shfl(my, j, 8);
            float4 v = h4[(size_t)idx * 8 + l8];
            acc.x += v.x; acc.y += v.y; acc.z += v.z; acc.w += v.w;
        }
    }
    for (; e < end; ++e) {
        int idx = col_idx[e];
        float4 v = h4[(size_t)idx * 8 + l8];
        acc.x += v.x; acc.y += v.y; acc.z += v.z; acc.w += v.w;
    }

    float ideg = inv_deg[n];
    int g = graph_ids[n];
    int g0 = __builtin_amdgcn_readfirstlane(g);
    bool g_uniform = __all(g == g0);

    if (OUT_COLS == NFEAT) {
        float4 o = *(const float4*)&b[f0];
#pragma unroll
        for (int sl = 0; sl < 8; ++sl) {
            float a0 = __shfl(acc.x, sl, 8);
            float a1 = __shfl(acc.y, sl, 8);
            float a2 = __shfl(acc.z, sl, 8);
            float a3 = __shfl(acc.w, sl, 8);
            float4 w0 = *(const float4*)&W[(sl * 4 + 0) * NFEAT + f0];
            float4 w1 = *(const float4*)&W[(sl * 4 + 1) * NFEAT + f0];
            float4 w2 = *(const float4*)&W[(sl * 4 + 2) * NFEAT + f0];
            float4 w3 = *(const float4*)&W[(sl * 4 + 3) * NFEAT + f0];
            o.x += a0 * w0.x + a1 * w1.x + a2 * w2.x + a3 * w3.x;
            o.y += a0 * w0.y + a1 * w1.y + a2 * w2.y + a3 * w3.y;
            o.z += a0 * w0.z + a1 * w1.z + a2 * w2.z + a3 * w3.z;
            o.w += a0 * w0.w + a1 * w1.w + a2 * w2.w + a3 * w3.w;
        }
        float4 v;
        v.x = tanhf(o.x * ideg);
        v.y = tanhf(o.y * ideg);
        v.z = tanhf(o.z * ideg);
        v.w = tanhf(o.w * ideg);
        if (valid)
            *(float4*)&h_out[(size_t)n * NFEAT + f0] = v;

        float4 c;
        c.x = valid ? v.x : 0.0f;
        c.y = valid ? v.y : 0.0f;
        c.z = valid ? v.z : 0.0f;
        c.w = valid ? v.w : 0.0f;
        if (g_uniform) {
            // sum across the 8 node-groups of the wave (lane bits 3,4,5)
            c.x += __shfl_xor(c.x, 8);  c.x += __shfl_xor(c.x, 16);  c.x += __shfl_xor(c.x, 32);
            c.y += __shfl_xor(c.y, 8);  c.y += __shfl_xor(c.y, 16);  c.y += __shfl_xor(c.y, 32);
            c.z += __shfl_xor(c.z, 8);  c.z += __shfl_xor(c.z, 16);  c.z += __shfl_xor(c.z, 32);
            c.w += __shfl_xor(c.w, 8);  c.w += __shfl_xor(c.w, 16);  c.w += __shfl_xor(c.w, 32);
            if (lane < 8) {
                float* p = &pooled[g0 * TOTLAT + pool_col + f0];
                atomicAdd(p + 0, c.x);
                atomicAdd(p + 1, c.y);
                atomicAdd(p + 2, c.z);
                atomicAdd(p + 3, c.w);
            }
        } else if (valid) {
            float* p = &pooled[g * TOTLAT + pool_col + f0];
            atomicAdd(p + 0, v.x);
            atomicAdd(p + 1, v.y);
            atomicAdd(p + 2, v.z);
            atomicAdd(p + 3, v.w);
        }
    } else {
        // single output column
        float4 wv = *(const float4*)&W[f0];
        float p = acc.x * wv.x + acc.y * wv.y + acc.z * wv.z + acc.w * wv.w;
        p += __shfl_xor(p, 1);
        p += __shfl_xor(p, 2);
        p += __shfl_xor(p, 4);
        float v = tanhf((p + b[0]) * ideg);
        float c = (valid && l8 == 0) ? v : 0.0f;
        if (g_uniform) {
            c += __shfl_xor(c, 8); c += __shfl_xor(c, 16); c += __shfl_xor(c, 32);
            if (lane == 0)
                atomicAdd(&pooled[g0 * TOTLAT + pool_col], c);
        } else if (valid && l8 == 0) {
            atomicAdd(&pooled[g * TOTLAT + pool_col], v);
        }
    }
}

__global__ void final_kernel(const float* __restrict__ pooled, const float* __restrict__ Wout,
                             const float* __restrict__ bout, float* __restrict__ out) {
    int g = blockIdx.x;    // 64
    int o = threadIdx.x;   // 128
    float s = bout[o];
#pragma unroll 4
    for (int k = 0; k < TOTLAT; ++k)
        s += pooled[g * TOTLAT + k] * Wout[k * OUTDIM + o];
    out[g * OUTDIM + o] = fmaxf(s, 0.0f);
}

extern "C" void kernel_launch(void* const* d_in, const int* in_sizes, int n_in,
                              void* d_out, int out_size, void* d_ws, size_t ws_size,
                              hipStream_t stream) {
    const float* node_feat = (const float*)d_in[0];
    const int*   src       = (const int*)d_in[1];
    const int*   dst       = (const int*)d_in[2];
    const int*   graph_ids = (const int*)d_in[3];
    const float* W0 = (const float*)d_in[5];
    const float* b0 = (const float*)d_in[6];
    const float* W1 = (const float*)d_in[7];
    const float* b1 = (const float*)d_in[8];
    const float* W2 = (const float*)d_in[9];
    const float* b2 = (const float*)d_in[10];
    const float* W3 = (const float*)d_in[11];
    const float* b3 = (const float*)d_in[12];
    const float* Wout = (const float*)d_in[13];
    const float* bout = (const float*)d_in[14];
    float* out = (float*)d_out;

    const int N = in_sizes[0] / NFEAT;   // 100000
    const int E = in_sizes[1];           // 3200000

    char* ws = (char*)d_ws;
    size_t off = 0;
    auto carve = [&](size_t bytes) -> void* {
        void* p = ws + off;
        off = (off + bytes + 255) & ~(size_t)255;
        return p;
    };
    int*   cnt       = (int*)carve((size_t)(N + 1) * 4);
    int*   row_ptr   = (int*)carve((size_t)(N + 1) * 4);
    int*   cursor    = (int*)carve((size_t)N * 4);
    int*   col_idx   = (int*)carve((size_t)E * 4);
    float* inv_deg   = (float*)carve((size_t)N * 4);
    float* hA        = (float*)carve((size_t)N * NFEAT * 4);
    float* hB        = (float*)carve((size_t)N * NFEAT * 4);
    float* pooled    = (float*)carve((size_t)NGRAPH * TOTLAT * 4);
    int*   blockSums = (int*)carve(4096);
    int*   blockOffs = (int*)carve(4096);

    hipMemsetAsync(cnt, 0, (size_t)(N + 1) * 4, stream);
    hipMemsetAsync(pooled, 0, (size_t)NGRAPH * TOTLAT * 4, stream);

    const int EBLK = 1024;
    count_kernel<<<EBLK, 256, 0, stream>>>(dst, cnt, E);

    const int nblk = (N + SCAN_SEG - 1) / SCAN_SEG;
    scan_a<<<nblk, SCAN_SEG, 0, stream>>>(cnt, blockSums, N);
    scan_b<<<1, SCAN_SEG, 0, stream>>>(blockSums, blockOffs, nblk);
    scan_c<<<nblk, SCAN_SEG, 0, stream>>>(cnt, blockOffs, row_ptr, cursor, inv_deg, N);
    fill_kernel<<<EBLK, 256, 0, stream>>>(src, dst, cursor, col_idx, E);

    const int lblocks = (N * 8 + 255) / 256;
    layer_kernel<32><<<lblocks, 256, 0, stream>>>(node_feat, hA, W0, b0, row_ptr, col_idx,
                                                  inv_deg, graph_ids, pooled, 0, N);
    layer_kernel<32><<<lblocks, 256, 0, stream>>>(hA, hB, W1, b1, row_ptr, col_idx,
                                                  inv_deg, graph_ids, pooled, 32, N);
    layer_kernel<32><<<lblocks, 256, 0, stream>>>(hB, hA, W2, b2, row_ptr, col_idx,
                                                  inv_deg, graph_ids, pooled, 64, N);
    layer_kernel<1><<<lblocks, 256, 0, stream>>>(hA, nullptr, W3, b3, row_ptr, col_idx,
                                                 inv_deg, graph_ids, pooled, 96, N);

    final_kernel<<<NGRAPH, OUTDIM, 0, stream>>>(pooled, Wout, bout, out);
}

// Round 5
// 681.354 us; speedup vs baseline: 2.0429x; 1.4397x over previous
//
#include <hip/hip_runtime.h>
#include <hip/hip_bf16.h>

// Graph net: 4x (agg = A@h + h; h = tanh((agg@W + b)/deg1)); concat -> graph sum-pool -> relu(linear)
// N=100000 nodes, E=3200000 edges, G=64 graphs, feats 32, latent [32,32,32,1], out 128.
//
// R5: CSR build rewritten as bucketed two-phase partition.
// R4 evidence: fill_kernel 255us with WRITE_SIZE=195MB (4B scatter -> 64B line
// thrash over 12.8MB range); count_kernel ~200us (3.2M random global atomics).
// Fix: partition edges into 196 buckets (512 nodes each) with LDS histograms;
// all degree-count / fill atomics become LDS-local; all global writes confined
// to small L2-resident windows (lines fully dirtied -> coalesced writeback).

#define NFEAT 32
#define TOTLAT 97
#define NGRAPH 64
#define OUTDIM 128
#define BSHIFT 9            // 512 nodes per bucket
#define NPB 512             // nodes per bucket
#define MAXBUCK 256
#define CH 8192             // edges per partition chunk/block

// Phase A1: per-chunk LDS histogram of bucket sizes
__global__ __launch_bounds__(256) void hist_kernel(const int* __restrict__ dst,
                                                   int* __restrict__ bucket_cnt,
                                                   int E, int nbuck) {
    __shared__ int h[MAXBUCK];
    for (int i = threadIdx.x; i < nbuck; i += blockDim.x) h[i] = 0;
    __syncthreads();
    int e0 = blockIdx.x * CH, e1 = min(e0 + CH, E);
    const int4* d4 = (const int4*)dst;
    int k0 = e0 >> 2, nk = (e1 - e0) >> 2;
    for (int k = k0 + threadIdx.x; k < k0 + nk; k += blockDim.x) {
        int4 v = d4[k];
        atomicAdd(&h[v.x >> BSHIFT], 1);
        atomicAdd(&h[v.y >> BSHIFT], 1);
        atomicAdd(&h[v.z >> BSHIFT], 1);
        atomicAdd(&h[v.w >> BSHIFT], 1);
    }
    for (int e = e0 + (nk << 2) + threadIdx.x; e < e1; e += blockDim.x)
        atomicAdd(&h[dst[e] >> BSHIFT], 1);
    __syncthreads();
    for (int i = threadIdx.x; i < nbuck; i += blockDim.x)
        if (h[i]) atomicAdd(&bucket_cnt[i], h[i]);
}

// Phase A2: exclusive scan of bucket sizes (nbuck <= 256)
__global__ void bucket_scan_kernel(const int* __restrict__ bucket_cnt,
                                   int* __restrict__ bucket_start,
                                   int* __restrict__ bucket_cursor,
                                   int* __restrict__ row_ptr,
                                   int N, int E, int nbuck) {
    __shared__ int s[MAXBUCK];
    int i = threadIdx.x;
    int v = (i < nbuck) ? bucket_cnt[i] : 0;
    s[i] = v;
    __syncthreads();
    for (int d = 1; d < MAXBUCK; d <<= 1) {
        int t = (i >= d) ? s[i - d] : 0;
        __syncthreads();
        if (i >= d) s[i] += t;
        __syncthreads();
    }
    if (i < nbuck) {
        int excl = s[i] - v;
        bucket_start[i] = excl;
        bucket_cursor[i] = excl;
    }
    if (i == 0) { bucket_start[nbuck] = E; row_ptr[N] = E; }
}

// Phase A3: partition (src,dst) pairs into bucket-contiguous regions.
// Writes land in ~(CH/nbuck)*8B contiguous runs per (chunk,bucket) -> L2-coalesced.
__global__ __launch_bounds__(256) void part_kernel(const int* __restrict__ src,
                                                   const int* __restrict__ dst,
                                                   int* __restrict__ bucket_cursor,
                                                   int2* __restrict__ pairs,
                                                   int E, int nbuck) {
    __shared__ int h[MAXBUCK];
    __shared__ int gb[MAXBUCK];
    for (int i = threadIdx.x; i < nbuck; i += blockDim.x) h[i] = 0;
    __syncthreads();
    int e0 = blockIdx.x * CH, e1 = min(e0 + CH, E);
    const int4* d4 = (const int4*)dst;
    const int4* s4 = (const int4*)src;
    int k0 = e0 >> 2, nk = (e1 - e0) >> 2;
    for (int k = k0 + threadIdx.x; k < k0 + nk; k += blockDim.x) {
        int4 v = d4[k];
        atomicAdd(&h[v.x >> BSHIFT], 1);
        atomicAdd(&h[v.y >> BSHIFT], 1);
        atomicAdd(&h[v.z >> BSHIFT], 1);
        atomicAdd(&h[v.w >> BSHIFT], 1);
    }
    for (int e = e0 + (nk << 2) + threadIdx.x; e < e1; e += blockDim.x)
        atomicAdd(&h[dst[e] >> BSHIFT], 1);
    __syncthreads();
    for (int i = threadIdx.x; i < nbuck; i += blockDim.x) {
        int c = h[i];
        gb[i] = c ? atomicAdd(&bucket_cursor[i], c) : 0;
        h[i] = 0;   // reuse as local rank cursor
    }
    __syncthreads();
    for (int k = k0 + threadIdx.x; k < k0 + nk; k += blockDim.x) {
        int4 d = d4[k];
        int4 s = s4[k];
        int b, r;
        b = d.x >> BSHIFT; r = atomicAdd(&h[b], 1); pairs[gb[b] + r] = make_int2(s.x, d.x);
        b = d.y >> BSHIFT; r = atomicAdd(&h[b], 1); pairs[gb[b] + r] = make_int2(s.y, d.y);
        b = d.z >> BSHIFT; r = atomicAdd(&h[b], 1); pairs[gb[b] + r] = make_int2(s.z, d.z);
        b = d.w >> BSHIFT; r = atomicAdd(&h[b], 1); pairs[gb[b] + r] = make_int2(s.w, d.w);
    }
    for (int e = e0 + (nk << 2) + threadIdx.x; e < e1; e += blockDim.x) {
        int dv = dst[e];
        int b = dv >> BSHIFT;
        int r = atomicAdd(&h[b], 1);
        pairs[gb[b] + r] = make_int2(src[e], dv);
    }
}

// Phase B: one block per bucket -> degree count, scan, col_idx fill, all LDS-local.
__global__ __launch_bounds__(NPB) void csr_kernel(const int2* __restrict__ pairs,
                                                  const int* __restrict__ bucket_start,
                                                  int* __restrict__ row_ptr,
                                                  int* __restrict__ col_idx,
                                                  float* __restrict__ inv_deg, int N) {
    __shared__ int deg[NPB];
    __shared__ int scn[NPB];
    int b = blockIdx.x;
    int n0 = b << BSHIFT;
    int tid = threadIdx.x;
    deg[tid] = 0;
    __syncthreads();
    int e0 = bucket_start[b], e1 = bucket_start[b + 1];
    for (int e = e0 + tid; e < e1; e += NPB) {
        int2 p = pairs[e];
        atomicAdd(&deg[p.y - n0], 1);
    }
    __syncthreads();
    int v = deg[tid];
    scn[tid] = v;
    __syncthreads();
    for (int d = 1; d < NPB; d <<= 1) {
        int t = (tid >= d) ? scn[tid - d] : 0;
        __syncthreads();
        if (tid >= d) scn[tid] += t;
        __syncthreads();
    }
    int excl = scn[tid] - v;
    int n = n0 + tid;
    if (n < N) {
        row_ptr[n] = e0 + excl;
        inv_deg[n] = 1.0f / ((float)v + 1.0f);
    }
    deg[tid] = excl;   // reuse as fill cursor
    __syncthreads();
    for (int e = e0 + tid; e < e1; e += NPB) {
        int2 p = pairs[e];
        int r = atomicAdd(&deg[p.y - n0], 1);
        col_idx[e0 + r] = p.x;   // write within bucket's L2-resident window
    }
}

// 8 lanes per node, lane owns feature quad f0 = (t&7)*4. float4 gathers.
template <int OUT_COLS>
__global__ __launch_bounds__(256) void layer_kernel(
    const float* __restrict__ h_in, float* __restrict__ h_out,
    const float* __restrict__ W, const float* __restrict__ b,
    const int* __restrict__ row_ptr, const int* __restrict__ col_idx,
    const float* __restrict__ inv_deg, const int* __restrict__ graph_ids,
    float* __restrict__ pooled, int pool_col, int N)
{
    const int t = blockIdx.x * blockDim.x + threadIdx.x;
    int n = t >> 3;
    const int l8 = t & 7;
    const int f0 = l8 * 4;
    const int lane = threadIdx.x & 63;
    const bool valid = n < N;
    if (!valid) n = N - 1;   // keep wave fully active for shfl/__all

    const float4* __restrict__ h4 = (const float4*)h_in;

    int beg = row_ptr[n];
    int end = row_ptr[n + 1];
    float4 acc = h4[(size_t)n * 8 + l8];   // self term

    int len = end - beg;
    int nfull = beg + (len & ~7);
    int e = beg;
    for (; e < nfull; e += 8) {
        int my = col_idx[e + l8];          // one coalesced idx load per chunk
#pragma unroll
        for (int j = 0; j < 8; ++j) {
            int idx = __shfl(my, j, 8);
            float4 v = h4[(size_t)idx * 8 + l8];
            acc.x += v.x; acc.y += v.y; acc.z += v.z; acc.w += v.w;
        }
    }
    for (; e < end; ++e) {
        int idx = col_idx[e];
        float4 v = h4[(size_t)idx * 8 + l8];
        acc.x += v.x; acc.y += v.y; acc.z += v.z; acc.w += v.w;
    }

    float ideg = inv_deg[n];
    int g = graph_ids[n];
    int g0 = __builtin_amdgcn_readfirstlane(g);
    bool g_uniform = __all(g == g0);

    if (OUT_COLS == NFEAT) {
        float4 o = *(const float4*)&b[f0];
#pragma unroll
        for (int sl = 0; sl < 8; ++sl) {
            float a0 = __shfl(acc.x, sl, 8);
            float a1 = __shfl(acc.y, sl, 8);
            float a2 = __shfl(acc.z, sl, 8);
            float a3 = __shfl(acc.w, sl, 8);
            float4 w0 = *(const float4*)&W[(sl * 4 + 0) * NFEAT + f0];
            float4 w1 = *(const float4*)&W[(sl * 4 + 1) * NFEAT + f0];
            float4 w2 = *(const float4*)&W[(sl * 4 + 2) * NFEAT + f0];
            float4 w3 = *(const float4*)&W[(sl * 4 + 3) * NFEAT + f0];
            o.x += a0 * w0.x + a1 * w1.x + a2 * w2.x + a3 * w3.x;
            o.y += a0 * w0.y + a1 * w1.y + a2 * w2.y + a3 * w3.y;
            o.z += a0 * w0.z + a1 * w1.z + a2 * w2.z + a3 * w3.z;
            o.w += a0 * w0.w + a1 * w1.w + a2 * w2.w + a3 * w3.w;
        }
        float4 v;
        v.x = tanhf(o.x * ideg);
        v.y = tanhf(o.y * ideg);
        v.z = tanhf(o.z * ideg);
        v.w = tanhf(o.w * ideg);
        if (valid)
            *(float4*)&h_out[(size_t)n * NFEAT + f0] = v;

        float4 c;
        c.x = valid ? v.x : 0.0f;
        c.y = valid ? v.y : 0.0f;
        c.z = valid ? v.z : 0.0f;
        c.w = valid ? v.w : 0.0f;
        if (g_uniform) {
            // sum across the 8 node-groups of the wave (lane bits 3,4,5)
            c.x += __shfl_xor(c.x, 8);  c.x += __shfl_xor(c.x, 16);  c.x += __shfl_xor(c.x, 32);
            c.y += __shfl_xor(c.y, 8);  c.y += __shfl_xor(c.y, 16);  c.y += __shfl_xor(c.y, 32);
            c.z += __shfl_xor(c.z, 8);  c.z += __shfl_xor(c.z, 16);  c.z += __shfl_xor(c.z, 32);
            c.w += __shfl_xor(c.w, 8);  c.w += __shfl_xor(c.w, 16);  c.w += __shfl_xor(c.w, 32);
            if (lane < 8) {
                float* p = &pooled[g0 * TOTLAT + pool_col + f0];
                atomicAdd(p + 0, c.x);
                atomicAdd(p + 1, c.y);
                atomicAdd(p + 2, c.z);
                atomicAdd(p + 3, c.w);
            }
        } else if (valid) {
            float* p = &pooled[g * TOTLAT + pool_col + f0];
            atomicAdd(p + 0, v.x);
            atomicAdd(p + 1, v.y);
            atomicAdd(p + 2, v.z);
            atomicAdd(p + 3, v.w);
        }
    } else {
        // single output column
        float4 wv = *(const float4*)&W[f0];
        float p = acc.x * wv.x + acc.y * wv.y + acc.z * wv.z + acc.w * wv.w;
        p += __shfl_xor(p, 1);
        p += __shfl_xor(p, 2);
        p += __shfl_xor(p, 4);
        float v = tanhf((p + b[0]) * ideg);
        float c = (valid && l8 == 0) ? v : 0.0f;
        if (g_uniform) {
            c += __shfl_xor(c, 8); c += __shfl_xor(c, 16); c += __shfl_xor(c, 32);
            if (lane == 0)
                atomicAdd(&pooled[g0 * TOTLAT + pool_col], c);
        } else if (valid && l8 == 0) {
            atomicAdd(&pooled[g * TOTLAT + pool_col], v);
        }
    }
}

__global__ void final_kernel(const float* __restrict__ pooled, const float* __restrict__ Wout,
                             const float* __restrict__ bout, float* __restrict__ out) {
    int g = blockIdx.x;    // 64
    int o = threadIdx.x;   // 128
    float s = bout[o];
#pragma unroll 4
    for (int k = 0; k < TOTLAT; ++k)
        s += pooled[g * TOTLAT + k] * Wout[k * OUTDIM + o];
    out[g * OUTDIM + o] = fmaxf(s, 0.0f);
}

extern "C" void kernel_launch(void* const* d_in, const int* in_sizes, int n_in,
                              void* d_out, int out_size, void* d_ws, size_t ws_size,
                              hipStream_t stream) {
    const float* node_feat = (const float*)d_in[0];
    const int*   src       = (const int*)d_in[1];
    const int*   dst       = (const int*)d_in[2];
    const int*   graph_ids = (const int*)d_in[3];
    const float* W0 = (const float*)d_in[5];
    const float* b0 = (const float*)d_in[6];
    const float* W1 = (const float*)d_in[7];
    const float* b1 = (const float*)d_in[8];
    const float* W2 = (const float*)d_in[9];
    const float* b2 = (const float*)d_in[10];
    const float* W3 = (const float*)d_in[11];
    const float* b3 = (const float*)d_in[12];
    const float* Wout = (const float*)d_in[13];
    const float* bout = (const float*)d_in[14];
    float* out = (float*)d_out;

    const int N = in_sizes[0] / NFEAT;   // 100000
    const int E = in_sizes[1];           // 3200000
    const int nbuck = (N + NPB - 1) >> BSHIFT;   // 196

    char* ws = (char*)d_ws;
    size_t off = 0;
    auto carve = [&](size_t bytes) -> void* {
        void* p = ws + off;
        off = (off + bytes + 255) & ~(size_t)255;
        return p;
    };
    int*   bucket_cnt    = (int*)carve((size_t)MAXBUCK * 4);
    int*   bucket_start  = (int*)carve((size_t)(MAXBUCK + 1) * 4);
    int*   bucket_cursor = (int*)carve((size_t)MAXBUCK * 4);
    int*   row_ptr       = (int*)carve((size_t)(N + 1) * 4);
    int*   col_idx       = (int*)carve((size_t)E * 4);
    float* inv_deg       = (float*)carve((size_t)N * 4);
    float* hA            = (float*)carve((size_t)N * NFEAT * 4);
    float* hB            = (float*)carve((size_t)N * NFEAT * 4);
    float* pooled        = (float*)carve((size_t)NGRAPH * TOTLAT * 4);
    // pairs (E*8B = 25.6MB) aliases hA+hB (25.6MB, contiguous; dead before layer 1 writes hA)
    int2*  pairs         = (int2*)hA;

    hipMemsetAsync(bucket_cnt, 0, (size_t)MAXBUCK * 4, stream);
    hipMemsetAsync(pooled, 0, (size_t)NGRAPH * TOTLAT * 4, stream);

    const int nchunks = (E + CH - 1) / CH;   // 391
    hist_kernel<<<nchunks, 256, 0, stream>>>(dst, bucket_cnt, E, nbuck);
    bucket_scan_kernel<<<1, MAXBUCK, 0, stream>>>(bucket_cnt, bucket_start, bucket_cursor,
                                                  row_ptr, N, E, nbuck);
    part_kernel<<<nchunks, 256, 0, stream>>>(src, dst, bucket_cursor, pairs, E, nbuck);
    csr_kernel<<<nbuck, NPB, 0, stream>>>(pairs, bucket_start, row_ptr, col_idx, inv_deg, N);

    const int lblocks = (N * 8 + 255) / 256;
    layer_kernel<32><<<lblocks, 256, 0, stream>>>(node_feat, hA, W0, b0, row_ptr, col_idx,
                                                  inv_deg, graph_ids, pooled, 0, N);
    layer_kernel<32><<<lblocks, 256, 0, stream>>>(hA, hB, W1, b1, row_ptr, col_idx,
                                                  inv_deg, graph_ids, pooled, 32, N);
    layer_kernel<32><<<lblocks, 256, 0, stream>>>(hB, hA, W2, b2, row_ptr, col_idx,
                                                  inv_deg, graph_ids, pooled, 64, N);
    layer_kernel<1><<<lblocks, 256, 0, stream>>>(hA, nullptr, W3, b3, row_ptr, col_idx,
                                                 inv_deg, graph_ids, pooled, 96, N);

    final_kernel<<<NGRAPH, OUTDIM, 0, stream>>>(pooled, Wout, bout, out);
}

// Round 8
// 591.304 us; speedup vs baseline: 2.3541x; 1.1523x over previous
//
#include <hip/hip_runtime.h>
#include <hip/hip_bf16.h>

// Graph net: 4x (agg = A@h + h; h = tanh((agg@W + b)/deg1)); concat -> graph sum-pool -> relu(linear)
// N=100000 nodes, E=3200000 edges, G=64 graphs, feats 32, latent [32,32,32,1], out 128.
//
// R8 == R6 resubmit (R6/R7 hit infra failures, never measured).
// R6: layer kernel latency fix. R5 evidence: layers 4x153us, VALUBusy 7%,
// HBM 14.7%, FETCH ~156MB (near the per-XCD replication floor) -> latency-bound,
// 2 serialized memory latencies per 8 edges. Fix: 32-edge chunks (4 idx loads,
// 32 gathers in flight -> 2 latencies per 32 edges), virtual padding via
// index-clamp-to-self + exact k*self subtraction (no tail code, no alignment),
// nontemporal col_idx loads (don't thrash h out of L2).

#define NFEAT 32
#define TOTLAT 97
#define NGRAPH 64
#define OUTDIM 128
#define BSHIFT 9            // 512 nodes per bucket
#define NPB 512             // nodes per bucket
#define MAXBUCK 256
#define CH 8192             // edges per partition chunk/block

// Phase A1: per-chunk LDS histogram of bucket sizes
__global__ __launch_bounds__(256) void hist_kernel(const int* __restrict__ dst,
                                                   int* __restrict__ bucket_cnt,
                                                   int E, int nbuck) {
    __shared__ int h[MAXBUCK];
    for (int i = threadIdx.x; i < nbuck; i += blockDim.x) h[i] = 0;
    __syncthreads();
    int e0 = blockIdx.x * CH, e1 = min(e0 + CH, E);
    const int4* d4 = (const int4*)dst;
    int k0 = e0 >> 2, nk = (e1 - e0) >> 2;
    for (int k = k0 + threadIdx.x; k < k0 + nk; k += blockDim.x) {
        int4 v = d4[k];
        atomicAdd(&h[v.x >> BSHIFT], 1);
        atomicAdd(&h[v.y >> BSHIFT], 1);
        atomicAdd(&h[v.z >> BSHIFT], 1);
        atomicAdd(&h[v.w >> BSHIFT], 1);
    }
    for (int e = e0 + (nk << 2) + threadIdx.x; e < e1; e += blockDim.x)
        atomicAdd(&h[dst[e] >> BSHIFT], 1);
    __syncthreads();
    for (int i = threadIdx.x; i < nbuck; i += blockDim.x)
        if (h[i]) atomicAdd(&bucket_cnt[i], h[i]);
}

// Phase A2: exclusive scan of bucket sizes (nbuck <= 256)
__global__ void bucket_scan_kernel(const int* __restrict__ bucket_cnt,
                                   int* __restrict__ bucket_start,
                                   int* __restrict__ bucket_cursor,
                                   int* __restrict__ row_ptr,
                                   int N, int E, int nbuck) {
    __shared__ int s[MAXBUCK];
    int i = threadIdx.x;
    int v = (i < nbuck) ? bucket_cnt[i] : 0;
    s[i] = v;
    __syncthreads();
    for (int d = 1; d < MAXBUCK; d <<= 1) {
        int t = (i >= d) ? s[i - d] : 0;
        __syncthreads();
        if (i >= d) s[i] += t;
        __syncthreads();
    }
    if (i < nbuck) {
        int excl = s[i] - v;
        bucket_start[i] = excl;
        bucket_cursor[i] = excl;
    }
    if (i == 0) { bucket_start[nbuck] = E; row_ptr[N] = E; }
}

// Phase A3: partition (src,dst) pairs into bucket-contiguous regions.
__global__ __launch_bounds__(256) void part_kernel(const int* __restrict__ src,
                                                   const int* __restrict__ dst,
                                                   int* __restrict__ bucket_cursor,
                                                   int2* __restrict__ pairs,
                                                   int E, int nbuck) {
    __shared__ int h[MAXBUCK];
    __shared__ int gb[MAXBUCK];
    for (int i = threadIdx.x; i < nbuck; i += blockDim.x) h[i] = 0;
    __syncthreads();
    int e0 = blockIdx.x * CH, e1 = min(e0 + CH, E);
    const int4* d4 = (const int4*)dst;
    const int4* s4 = (const int4*)src;
    int k0 = e0 >> 2, nk = (e1 - e0) >> 2;
    for (int k = k0 + threadIdx.x; k < k0 + nk; k += blockDim.x) {
        int4 v = d4[k];
        atomicAdd(&h[v.x >> BSHIFT], 1);
        atomicAdd(&h[v.y >> BSHIFT], 1);
        atomicAdd(&h[v.z >> BSHIFT], 1);
        atomicAdd(&h[v.w >> BSHIFT], 1);
    }
    for (int e = e0 + (nk << 2) + threadIdx.x; e < e1; e += blockDim.x)
        atomicAdd(&h[dst[e] >> BSHIFT], 1);
    __syncthreads();
    for (int i = threadIdx.x; i < nbuck; i += blockDim.x) {
        int c = h[i];
        gb[i] = c ? atomicAdd(&bucket_cursor[i], c) : 0;
        h[i] = 0;   // reuse as local rank cursor
    }
    __syncthreads();
    for (int k = k0 + threadIdx.x; k < k0 + nk; k += blockDim.x) {
        int4 d = d4[k];
        int4 s = s4[k];
        int b, r;
        b = d.x >> BSHIFT; r = atomicAdd(&h[b], 1); pairs[gb[b] + r] = make_int2(s.x, d.x);
        b = d.y >> BSHIFT; r = atomicAdd(&h[b], 1); pairs[gb[b] + r] = make_int2(s.y, d.y);
        b = d.z >> BSHIFT; r = atomicAdd(&h[b], 1); pairs[gb[b] + r] = make_int2(s.z, d.z);
        b = d.w >> BSHIFT; r = atomicAdd(&h[b], 1); pairs[gb[b] + r] = make_int2(s.w, d.w);
    }
    for (int e = e0 + (nk << 2) + threadIdx.x; e < e1; e += blockDim.x) {
        int dv = dst[e];
        int b = dv >> BSHIFT;
        int r = atomicAdd(&h[b], 1);
        pairs[gb[b] + r] = make_int2(src[e], dv);
    }
}

// Phase B: one block per bucket -> degree count, scan, col_idx fill, all LDS-local.
__global__ __launch_bounds__(NPB) void csr_kernel(const int2* __restrict__ pairs,
                                                  const int* __restrict__ bucket_start,
                                                  int* __restrict__ row_ptr,
                                                  int* __restrict__ col_idx,
                                                  float* __restrict__ inv_deg, int N) {
    __shared__ int deg[NPB];
    __shared__ int scn[NPB];
    int b = blockIdx.x;
    int n0 = b << BSHIFT;
    int tid = threadIdx.x;
    deg[tid] = 0;
    __syncthreads();
    int e0 = bucket_start[b], e1 = bucket_start[b + 1];
    for (int e = e0 + tid; e < e1; e += NPB) {
        int2 p = pairs[e];
        atomicAdd(&deg[p.y - n0], 1);
    }
    __syncthreads();
    int v = deg[tid];
    scn[tid] = v;
    __syncthreads();
    for (int d = 1; d < NPB; d <<= 1) {
        int t = (tid >= d) ? scn[tid - d] : 0;
        __syncthreads();
        if (tid >= d) scn[tid] += t;
        __syncthreads();
    }
    int excl = scn[tid] - v;
    int n = n0 + tid;
    if (n < N) {
        row_ptr[n] = e0 + excl;
        inv_deg[n] = 1.0f / ((float)v + 1.0f);
    }
    deg[tid] = excl;   // reuse as fill cursor
    __syncthreads();
    for (int e = e0 + tid; e < e1; e += NPB) {
        int2 p = pairs[e];
        int r = atomicAdd(&deg[p.y - n0], 1);
        col_idx[e0 + r] = p.x;   // write within bucket's L2-resident window
    }
}

// 8 lanes per node, lane owns feature quad f0 = (t&7)*4.
// 32-edge chunks: 4 idx loads + 32 gathers in flight; OOR slots clamp to self,
// corrected by acc -= k*self afterwards.
template <int OUT_COLS>
__global__ __launch_bounds__(256) void layer_kernel(
    const float* __restrict__ h_in, float* __restrict__ h_out,
    const float* __restrict__ W, const float* __restrict__ b,
    const int* __restrict__ row_ptr, const int* __restrict__ col_idx,
    const float* __restrict__ inv_deg, const int* __restrict__ graph_ids,
    float* __restrict__ pooled, int pool_col, int N)
{
    const int t = blockIdx.x * blockDim.x + threadIdx.x;
    int n = t >> 3;
    const int l8 = t & 7;
    const int f0 = l8 * 4;
    const int lane = threadIdx.x & 63;
    const bool valid = n < N;
    if (!valid) n = N - 1;   // keep wave fully active for shfl/__all

    const float4* __restrict__ h4 = (const float4*)h_in;

    int beg = row_ptr[n];
    int end = row_ptr[n + 1];
    int len = end - beg;
    float4 self = h4[(size_t)n * 8 + l8];
    float4 acc = self;   // the "+ h" self term

    for (int e = beg; e < end; e += 32) {
        int base = e + l8 * 4;
        int my0 = __builtin_nontemporal_load(&col_idx[base + 0]);
        int my1 = __builtin_nontemporal_load(&col_idx[base + 1]);
        int my2 = __builtin_nontemporal_load(&col_idx[base + 2]);
        int my3 = __builtin_nontemporal_load(&col_idx[base + 3]);
        int rem = end - e;   // uniform within the 8-lane group
#pragma unroll
        for (int sl = 0; sl < 8; ++sl) {
            int i0 = __shfl(my0, sl, 8);
            int i1 = __shfl(my1, sl, 8);
            int i2 = __shfl(my2, sl, 8);
            int i3 = __shfl(my3, sl, 8);
            int j = sl * 4;
            i0 = (j + 0 < rem) ? i0 : n;
            i1 = (j + 1 < rem) ? i1 : n;
            i2 = (j + 2 < rem) ? i2 : n;
            i3 = (j + 3 < rem) ? i3 : n;
            float4 v0 = h4[(size_t)i0 * 8 + l8];
            float4 v1 = h4[(size_t)i1 * 8 + l8];
            float4 v2 = h4[(size_t)i2 * 8 + l8];
            float4 v3 = h4[(size_t)i3 * 8 + l8];
            acc.x += v0.x; acc.y += v0.y; acc.z += v0.z; acc.w += v0.w;
            acc.x += v1.x; acc.y += v1.y; acc.z += v1.z; acc.w += v1.w;
            acc.x += v2.x; acc.y += v2.y; acc.z += v2.z; acc.w += v2.w;
            acc.x += v3.x; acc.y += v3.y; acc.z += v3.z; acc.w += v3.w;
        }
    }
    // remove the k padded self-contributions (exact)
    float fk = (float)(((len + 31) & ~31) - len);
    acc.x -= fk * self.x; acc.y -= fk * self.y;
    acc.z -= fk * self.z; acc.w -= fk * self.w;

    float ideg = inv_deg[n];
    int g = graph_ids[n];
    int g0 = __builtin_amdgcn_readfirstlane(g);
    bool g_uniform = __all(g == g0);

    if (OUT_COLS == NFEAT) {
        float4 o = *(const float4*)&b[f0];
#pragma unroll
        for (int sl = 0; sl < 8; ++sl) {
            float a0 = __shfl(acc.x, sl, 8);
            float a1 = __shfl(acc.y, sl, 8);
            float a2 = __shfl(acc.z, sl, 8);
            float a3 = __shfl(acc.w, sl, 8);
            float4 w0 = *(const float4*)&W[(sl * 4 + 0) * NFEAT + f0];
            float4 w1 = *(const float4*)&W[(sl * 4 + 1) * NFEAT + f0];
            float4 w2 = *(const float4*)&W[(sl * 4 + 2) * NFEAT + f0];
            float4 w3 = *(const float4*)&W[(sl * 4 + 3) * NFEAT + f0];
            o.x += a0 * w0.x + a1 * w1.x + a2 * w2.x + a3 * w3.x;
            o.y += a0 * w0.y + a1 * w1.y + a2 * w2.y + a3 * w3.y;
            o.z += a0 * w0.z + a1 * w1.z + a2 * w2.z + a3 * w3.z;
            o.w += a0 * w0.w + a1 * w1.w + a2 * w2.w + a3 * w3.w;
        }
        float4 v;
        v.x = tanhf(o.x * ideg);
        v.y = tanhf(o.y * ideg);
        v.z = tanhf(o.z * ideg);
        v.w = tanhf(o.w * ideg);
        if (valid)
            *(float4*)&h_out[(size_t)n * NFEAT + f0] = v;

        float4 c;
        c.x = valid ? v.x : 0.0f;
        c.y = valid ? v.y : 0.0f;
        c.z = valid ? v.z : 0.0f;
        c.w = valid ? v.w : 0.0f;
        if (g_uniform) {
            // sum across the 8 node-groups of the wave (lane bits 3,4,5)
            c.x += __shfl_xor(c.x, 8);  c.x += __shfl_xor(c.x, 16);  c.x += __shfl_xor(c.x, 32);
            c.y += __shfl_xor(c.y, 8);  c.y += __shfl_xor(c.y, 16);  c.y += __shfl_xor(c.y, 32);
            c.z += __shfl_xor(c.z, 8);  c.z += __shfl_xor(c.z, 16);  c.z += __shfl_xor(c.z, 32);
            c.w += __shfl_xor(c.w, 8);  c.w += __shfl_xor(c.w, 16);  c.w += __shfl_xor(c.w, 32);
            if (lane < 8) {
                float* p = &pooled[g0 * TOTLAT + pool_col + f0];
                atomicAdd(p + 0, c.x);
                atomicAdd(p + 1, c.y);
                atomicAdd(p + 2, c.z);
                atomicAdd(p + 3, c.w);
            }
        } else if (valid) {
            float* p = &pooled[g * TOTLAT + pool_col + f0];
            atomicAdd(p + 0, v.x);
            atomicAdd(p + 1, v.y);
            atomicAdd(p + 2, v.z);
            atomicAdd(p + 3, v.w);
        }
    } else {
        // single output column
        float4 wv = *(const float4*)&W[f0];
        float p = acc.x * wv.x + acc.y * wv.y + acc.z * wv.z + acc.w * wv.w;
        p += __shfl_xor(p, 1);
        p += __shfl_xor(p, 2);
        p += __shfl_xor(p, 4);
        float v = tanhf((p + b[0]) * ideg);
        float c = (valid && l8 == 0) ? v : 0.0f;
        if (g_uniform) {
            c += __shfl_xor(c, 8); c += __shfl_xor(c, 16); c += __shfl_xor(c, 32);
            if (lane == 0)
                atomicAdd(&pooled[g0 * TOTLAT + pool_col], c);
        } else if (valid && l8 == 0) {
            atomicAdd(&pooled[g * TOTLAT + pool_col], v);
        }
    }
}

__global__ void final_kernel(const float* __restrict__ pooled, const float* __restrict__ Wout,
                             const float* __restrict__ bout, float* __restrict__ out) {
    int g = blockIdx.x;    // 64
    int o = threadIdx.x;   // 128
    float s = bout[o];
#pragma unroll 4
    for (int k = 0; k < TOTLAT; ++k)
        s += pooled[g * TOTLAT + k] * Wout[k * OUTDIM + o];
    out[g * OUTDIM + o] = fmaxf(s, 0.0f);
}

extern "C" void kernel_launch(void* const* d_in, const int* in_sizes, int n_in,
                              void* d_out, int out_size, void* d_ws, size_t ws_size,
                              hipStream_t stream) {
    const float* node_feat = (const float*)d_in[0];
    const int*   src       = (const int*)d_in[1];
    const int*   dst       = (const int*)d_in[2];
    const int*   graph_ids = (const int*)d_in[3];
    const float* W0 = (const float*)d_in[5];
    const float* b0 = (const float*)d_in[6];
    const float* W1 = (const float*)d_in[7];
    const float* b1 = (const float*)d_in[8];
    const float* W2 = (const float*)d_in[9];
    const float* b2 = (const float*)d_in[10];
    const float* W3 = (const float*)d_in[11];
    const float* b3 = (const float*)d_in[12];
    const float* Wout = (const float*)d_in[13];
    const float* bout = (const float*)d_in[14];
    float* out = (float*)d_out;

    const int N = in_sizes[0] / NFEAT;   // 100000
    const int E = in_sizes[1];           // 3200000
    const int nbuck = (N + NPB - 1) >> BSHIFT;   // 196

    char* ws = (char*)d_ws;
    size_t off = 0;
    auto carve = [&](size_t bytes) -> void* {
        void* p = ws + off;
        off = (off + bytes + 255) & ~(size_t)255;
        return p;
    };
    int*   bucket_cnt    = (int*)carve((size_t)MAXBUCK * 4);
    int*   bucket_start  = (int*)carve((size_t)(MAXBUCK + 1) * 4);
    int*   bucket_cursor = (int*)carve((size_t)MAXBUCK * 4);
    int*   row_ptr       = (int*)carve((size_t)(N + 1) * 4);
    int*   col_idx       = (int*)carve((size_t)(E + 32) * 4);  // +32 slack for chunked over-read
    float* inv_deg       = (float*)carve((size_t)N * 4);
    float* hA            = (float*)carve((size_t)N * NFEAT * 4);
    float* hB            = (float*)carve((size_t)N * NFEAT * 4);
    float* pooled        = (float*)carve((size_t)NGRAPH * TOTLAT * 4);
    // pairs (E*8B = 25.6MB) aliases hA+hB (25.6MB, contiguous; dead before layer 1 writes hA)
    int2*  pairs         = (int2*)hA;

    hipMemsetAsync(bucket_cnt, 0, (size_t)MAXBUCK * 4, stream);
    hipMemsetAsync(pooled, 0, (size_t)NGRAPH * TOTLAT * 4, stream);

    const int nchunks = (E + CH - 1) / CH;   // 391
    hist_kernel<<<nchunks, 256, 0, stream>>>(dst, bucket_cnt, E, nbuck);
    bucket_scan_kernel<<<1, MAXBUCK, 0, stream>>>(bucket_cnt, bucket_start, bucket_cursor,
                                                  row_ptr, N, E, nbuck);
    part_kernel<<<nchunks, 256, 0, stream>>>(src, dst, bucket_cursor, pairs, E, nbuck);
    csr_kernel<<<nbuck, NPB, 0, stream>>>(pairs, bucket_start, row_ptr, col_idx, inv_deg, N);

    const int lblocks = (N * 8 + 255) / 256;
    layer_kernel<32><<<lblocks, 256, 0, stream>>>(node_feat, hA, W0, b0, row_ptr, col_idx,
                                                  inv_deg, graph_ids, pooled, 0, N);
    layer_kernel<32><<<lblocks, 256, 0, stream>>>(hA, hB, W1, b1, row_ptr, col_idx,
                                                  inv_deg, graph_ids, pooled, 32, N);
    layer_kernel<32><<<lblocks, 256, 0, stream>>>(hB, hA, W2, b2, row_ptr, col_idx,
                                                  inv_deg, graph_ids, pooled, 64, N);
    layer_kernel<1><<<lblocks, 256, 0, stream>>>(hA, nullptr, W3, b3, row_ptr, col_idx,
                                                 inv_deg, graph_ids, pooled, 96, N);

    final_kernel<<<NGRAPH, OUTDIM, 0, stream>>>(pooled, Wout, bout, out);
}

// Round 10
// 584.566 us; speedup vs baseline: 2.3812x; 1.0115x over previous
//
#include <hip/hip_runtime.h>
#include <hip/hip_bf16.h>

// Graph net: 4x (agg = A@h + h; h = tanh((agg@W + b)/deg1)); concat -> graph sum-pool -> relu(linear)
// N=100000, E=3200000, G=64, feats 32, latent [32,32,32,1], out 128.
//
// R10 == R9 resubmit (R9 hit an infra failure, never measured).
// R9: (1) layer-3 reassociation: (A@h+h)@W3 = A@(h@W3)+h@W3, W3 is 32x1 ->
//     gather over a 400KB scalar array instead of 12.8MB of rows; y=h2@W3 fused
//     into layer-2 MLP (h2 never written). (2) split agg/MLP for layers 0-2:
//     gather-only kernel with __launch_bounds__(256,8) (VGPR<=64 -> 8 waves/SIMD;
//     R8 evidence: 92 VGPR pinned occupancy at 18.5%); MLP runs in-place on the
//     agg buffer (no extra traffic).

#define NFEAT 32
#define TOTLAT 97
#define NGRAPH 64
#define OUTDIM 128
#define BSHIFT 9            // 512 nodes per bucket
#define NPB 512
#define MAXBUCK 256
#define CH 8192

// ---------------- CSR build (unchanged from R8) ----------------
__global__ __launch_bounds__(256) void hist_kernel(const int* __restrict__ dst,
                                                   int* __restrict__ bucket_cnt,
                                                   int E, int nbuck) {
    __shared__ int h[MAXBUCK];
    for (int i = threadIdx.x; i < nbuck; i += blockDim.x) h[i] = 0;
    __syncthreads();
    int e0 = blockIdx.x * CH, e1 = min(e0 + CH, E);
    const int4* d4 = (const int4*)dst;
    int k0 = e0 >> 2, nk = (e1 - e0) >> 2;
    for (int k = k0 + threadIdx.x; k < k0 + nk; k += blockDim.x) {
        int4 v = d4[k];
        atomicAdd(&h[v.x >> BSHIFT], 1);
        atomicAdd(&h[v.y >> BSHIFT], 1);
        atomicAdd(&h[v.z >> BSHIFT], 1);
        atomicAdd(&h[v.w >> BSHIFT], 1);
    }
    for (int e = e0 + (nk << 2) + threadIdx.x; e < e1; e += blockDim.x)
        atomicAdd(&h[dst[e] >> BSHIFT], 1);
    __syncthreads();
    for (int i = threadIdx.x; i < nbuck; i += blockDim.x)
        if (h[i]) atomicAdd(&bucket_cnt[i], h[i]);
}

__global__ void bucket_scan_kernel(const int* __restrict__ bucket_cnt,
                                   int* __restrict__ bucket_start,
                                   int* __restrict__ bucket_cursor,
                                   int* __restrict__ row_ptr,
                                   int N, int E, int nbuck) {
    __shared__ int s[MAXBUCK];
    int i = threadIdx.x;
    int v = (i < nbuck) ? bucket_cnt[i] : 0;
    s[i] = v;
    __syncthreads();
    for (int d = 1; d < MAXBUCK; d <<= 1) {
        int t = (i >= d) ? s[i - d] : 0;
        __syncthreads();
        if (i >= d) s[i] += t;
        __syncthreads();
    }
    if (i < nbuck) {
        int excl = s[i] - v;
        bucket_start[i] = excl;
        bucket_cursor[i] = excl;
    }
    if (i == 0) { bucket_start[nbuck] = E; row_ptr[N] = E; }
}

__global__ __launch_bounds__(256) void part_kernel(const int* __restrict__ src,
                                                   const int* __restrict__ dst,
                                                   int* __restrict__ bucket_cursor,
                                                   int2* __restrict__ pairs,
                                                   int E, int nbuck) {
    __shared__ int h[MAXBUCK];
    __shared__ int gb[MAXBUCK];
    for (int i = threadIdx.x; i < nbuck; i += blockDim.x) h[i] = 0;
    __syncthreads();
    int e0 = blockIdx.x * CH, e1 = min(e0 + CH, E);
    const int4* d4 = (const int4*)dst;
    const int4* s4 = (const int4*)src;
    int k0 = e0 >> 2, nk = (e1 - e0) >> 2;
    for (int k = k0 + threadIdx.x; k < k0 + nk; k += blockDim.x) {
        int4 v = d4[k];
        atomicAdd(&h[v.x >> BSHIFT], 1);
        atomicAdd(&h[v.y >> BSHIFT], 1);
        atomicAdd(&h[v.z >> BSHIFT], 1);
        atomicAdd(&h[v.w >> BSHIFT], 1);
    }
    for (int e = e0 + (nk << 2) + threadIdx.x; e < e1; e += blockDim.x)
        atomicAdd(&h[dst[e] >> BSHIFT], 1);
    __syncthreads();
    for (int i = threadIdx.x; i < nbuck; i += blockDim.x) {
        int c = h[i];
        gb[i] = c ? atomicAdd(&bucket_cursor[i], c) : 0;
        h[i] = 0;
    }
    __syncthreads();
    for (int k = k0 + threadIdx.x; k < k0 + nk; k += blockDim.x) {
        int4 d = d4[k];
        int4 s = s4[k];
        int b, r;
        b = d.x >> BSHIFT; r = atomicAdd(&h[b], 1); pairs[gb[b] + r] = make_int2(s.x, d.x);
        b = d.y >> BSHIFT; r = atomicAdd(&h[b], 1); pairs[gb[b] + r] = make_int2(s.y, d.y);
        b = d.z >> BSHIFT; r = atomicAdd(&h[b], 1); pairs[gb[b] + r] = make_int2(s.z, d.z);
        b = d.w >> BSHIFT; r = atomicAdd(&h[b], 1); pairs[gb[b] + r] = make_int2(s.w, d.w);
    }
    for (int e = e0 + (nk << 2) + threadIdx.x; e < e1; e += blockDim.x) {
        int dv = dst[e];
        int b = dv >> BSHIFT;
        int r = atomicAdd(&h[b], 1);
        pairs[gb[b] + r] = make_int2(src[e], dv);
    }
}

__global__ __launch_bounds__(NPB) void csr_kernel(const int2* __restrict__ pairs,
                                                  const int* __restrict__ bucket_start,
                                                  int* __restrict__ row_ptr,
                                                  int* __restrict__ col_idx,
                                                  float* __restrict__ inv_deg, int N) {
    __shared__ int deg[NPB];
    __shared__ int scn[NPB];
    int b = blockIdx.x;
    int n0 = b << BSHIFT;
    int tid = threadIdx.x;
    deg[tid] = 0;
    __syncthreads();
    int e0 = bucket_start[b], e1 = bucket_start[b + 1];
    for (int e = e0 + tid; e < e1; e += NPB) {
        int2 p = pairs[e];
        atomicAdd(&deg[p.y - n0], 1);
    }
    __syncthreads();
    int v = deg[tid];
    scn[tid] = v;
    __syncthreads();
    for (int d = 1; d < NPB; d <<= 1) {
        int t = (tid >= d) ? scn[tid - d] : 0;
        __syncthreads();
        if (tid >= d) scn[tid] += t;
        __syncthreads();
    }
    int excl = scn[tid] - v;
    int n = n0 + tid;
    if (n < N) {
        row_ptr[n] = e0 + excl;
        inv_deg[n] = 1.0f / ((float)v + 1.0f);
    }
    deg[tid] = excl;
    __syncthreads();
    for (int e = e0 + tid; e < e1; e += NPB) {
        int2 p = pairs[e];
        int r = atomicAdd(&deg[p.y - n0], 1);
        col_idx[e0 + r] = p.x;
    }
}

// ---------------- layers 0-2: gather-only (low VGPR, high occupancy) ----------------
// 8 lanes/node, float4 per lane. 32-edge chunks; OOR slots clamp to self,
// corrected by acc -= k*self. __launch_bounds__(256,8): force VGPR<=64.
__global__ __launch_bounds__(256, 8) void agg_kernel(
    const float* __restrict__ h_in, float* __restrict__ agg,
    const int* __restrict__ row_ptr, const int* __restrict__ col_idx, int N)
{
    const int t = blockIdx.x * blockDim.x + threadIdx.x;
    int n = t >> 3;
    const int l8 = t & 7;
    if (n >= N) return;

    const float4* __restrict__ h4 = (const float4*)h_in;

    int beg = row_ptr[n];
    int end = row_ptr[n + 1];
    int len = end - beg;
    float4 self = h4[(size_t)n * 8 + l8];
    float4 acc = self;

    for (int e = beg; e < end; e += 32) {
        int base = e + l8 * 4;
        int my0 = __builtin_nontemporal_load(&col_idx[base + 0]);
        int my1 = __builtin_nontemporal_load(&col_idx[base + 1]);
        int my2 = __builtin_nontemporal_load(&col_idx[base + 2]);
        int my3 = __builtin_nontemporal_load(&col_idx[base + 3]);
        int rem = end - e;
#pragma unroll
        for (int sl = 0; sl < 8; ++sl) {
            int i0 = __shfl(my0, sl, 8);
            int i1 = __shfl(my1, sl, 8);
            int i2 = __shfl(my2, sl, 8);
            int i3 = __shfl(my3, sl, 8);
            int j = sl * 4;
            i0 = (j + 0 < rem) ? i0 : n;
            i1 = (j + 1 < rem) ? i1 : n;
            i2 = (j + 2 < rem) ? i2 : n;
            i3 = (j + 3 < rem) ? i3 : n;
            float4 v0 = h4[(size_t)i0 * 8 + l8];
            float4 v1 = h4[(size_t)i1 * 8 + l8];
            float4 v2 = h4[(size_t)i2 * 8 + l8];
            float4 v3 = h4[(size_t)i3 * 8 + l8];
            acc.x += v0.x + v1.x + v2.x + v3.x;
            acc.y += v0.y + v1.y + v2.y + v3.y;
            acc.z += v0.z + v1.z + v2.z + v3.z;
            acc.w += v0.w + v1.w + v2.w + v3.w;
        }
    }
    float fk = (float)(((len + 31) & ~31) - len);
    acc.x -= fk * self.x; acc.y -= fk * self.y;
    acc.z -= fk * self.z; acc.w -= fk * self.w;

    ((float4*)agg)[(size_t)n * 8 + l8] = acc;
}

// ---------------- MLP (+pool, optionally emit y=h@W3), in-place on agg ----------------
template <bool EMIT_Y>
__global__ __launch_bounds__(256) void mlp_kernel(
    float* __restrict__ hbuf,                 // in: agg row; out: h row (in-place) unless EMIT_Y
    const float* __restrict__ W, const float* __restrict__ b,
    const float* __restrict__ inv_deg, const int* __restrict__ graph_ids,
    float* __restrict__ pooled, int pool_col,
    const float* __restrict__ W3, float* __restrict__ y, int N)
{
    const int t = blockIdx.x * blockDim.x + threadIdx.x;
    int n = t >> 3;
    const int l8 = t & 7;
    const int f0 = l8 * 4;
    const int lane = threadIdx.x & 63;
    const bool valid = n < N;
    if (!valid) n = N - 1;   // keep wave fully active for shfl/__all

    float4 acc = ((const float4*)hbuf)[(size_t)n * 8 + l8];
    float ideg = inv_deg[n];
    int g = graph_ids[n];
    int g0 = __builtin_amdgcn_readfirstlane(g);
    bool g_uniform = __all(g == g0);

    float4 o = *(const float4*)&b[f0];
#pragma unroll
    for (int sl = 0; sl < 8; ++sl) {
        float a0 = __shfl(acc.x, sl, 8);
        float a1 = __shfl(acc.y, sl, 8);
        float a2 = __shfl(acc.z, sl, 8);
        float a3 = __shfl(acc.w, sl, 8);
        float4 w0 = *(const float4*)&W[(sl * 4 + 0) * NFEAT + f0];
        float4 w1 = *(const float4*)&W[(sl * 4 + 1) * NFEAT + f0];
        float4 w2 = *(const float4*)&W[(sl * 4 + 2) * NFEAT + f0];
        float4 w3 = *(const float4*)&W[(sl * 4 + 3) * NFEAT + f0];
        o.x += a0 * w0.x + a1 * w1.x + a2 * w2.x + a3 * w3.x;
        o.y += a0 * w0.y + a1 * w1.y + a2 * w2.y + a3 * w3.y;
        o.z += a0 * w0.z + a1 * w1.z + a2 * w2.z + a3 * w3.z;
        o.w += a0 * w0.w + a1 * w1.w + a2 * w2.w + a3 * w3.w;
    }
    float4 v;
    v.x = tanhf(o.x * ideg);
    v.y = tanhf(o.y * ideg);
    v.z = tanhf(o.z * ideg);
    v.w = tanhf(o.w * ideg);

    if (!EMIT_Y) {
        if (valid)
            ((float4*)hbuf)[(size_t)n * 8 + l8] = v;
    } else {
        // y[n] = dot(h2_row, W3)  (bias added after layer-3 gather)
        float4 wv = *(const float4*)&W3[f0];
        float p = v.x * wv.x + v.y * wv.y + v.z * wv.z + v.w * wv.w;
        p += __shfl_xor(p, 1);
        p += __shfl_xor(p, 2);
        p += __shfl_xor(p, 4);
        if (valid && l8 == 0) y[n] = p;
    }

    // pooling for this layer's h columns
    float4 c;
    c.x = valid ? v.x : 0.0f;
    c.y = valid ? v.y : 0.0f;
    c.z = valid ? v.z : 0.0f;
    c.w = valid ? v.w : 0.0f;
    if (g_uniform) {
        c.x += __shfl_xor(c.x, 8);  c.x += __shfl_xor(c.x, 16);  c.x += __shfl_xor(c.x, 32);
        c.y += __shfl_xor(c.y, 8);  c.y += __shfl_xor(c.y, 16);  c.y += __shfl_xor(c.y, 32);
        c.z += __shfl_xor(c.z, 8);  c.z += __shfl_xor(c.z, 16);  c.z += __shfl_xor(c.z, 32);
        c.w += __shfl_xor(c.w, 8);  c.w += __shfl_xor(c.w, 16);  c.w += __shfl_xor(c.w, 32);
        if (lane < 8) {
            float* p = &pooled[g0 * TOTLAT + pool_col + f0];
            atomicAdd(p + 0, c.x);
            atomicAdd(p + 1, c.y);
            atomicAdd(p + 2, c.z);
            atomicAdd(p + 3, c.w);
        }
    } else if (valid) {
        float* p = &pooled[g * TOTLAT + pool_col + f0];
        atomicAdd(p + 0, v.x);
        atomicAdd(p + 1, v.y);
        atomicAdd(p + 2, v.z);
        atomicAdd(p + 3, v.w);
    }
}

// ---------------- layer 3: scalar gather over y (L2-resident 400KB) ----------------
__global__ __launch_bounds__(256) void agg3_kernel(
    const float* __restrict__ y, const float* __restrict__ b3,
    const int* __restrict__ row_ptr, const int* __restrict__ col_idx,
    const float* __restrict__ inv_deg, const int* __restrict__ graph_ids,
    float* __restrict__ pooled, int N)
{
    int n = blockIdx.x * blockDim.x + threadIdx.x;
    const bool valid = n < N;
    if (!valid) n = N - 1;

    int beg = row_ptr[n];
    int end = row_ptr[n + 1];
    float s = y[n];
    int e = beg;
    for (; e + 8 <= end; e += 8) {
        float a0 = y[col_idx[e + 0]];
        float a1 = y[col_idx[e + 1]];
        float a2 = y[col_idx[e + 2]];
        float a3 = y[col_idx[e + 3]];
        float a4 = y[col_idx[e + 4]];
        float a5 = y[col_idx[e + 5]];
        float a6 = y[col_idx[e + 6]];
        float a7 = y[col_idx[e + 7]];
        s += ((a0 + a1) + (a2 + a3)) + ((a4 + a5) + (a6 + a7));
    }
    for (; e < end; ++e)
        s += y[col_idx[e]];

    float v = tanhf((s + b3[0]) * inv_deg[n]);

    int g = graph_ids[n];
    int g0 = __builtin_amdgcn_readfirstlane(g);
    float c = valid ? v : 0.0f;
    if (__all(g == g0)) {
        c += __shfl_xor(c, 1);  c += __shfl_xor(c, 2);  c += __shfl_xor(c, 4);
        c += __shfl_xor(c, 8);  c += __shfl_xor(c, 16); c += __shfl_xor(c, 32);
        if ((threadIdx.x & 63) == 0)
            atomicAdd(&pooled[g0 * TOTLAT + 96], c);
    } else if (valid) {
        atomicAdd(&pooled[g * TOTLAT + 96], v);
    }
}

__global__ void final_kernel(const float* __restrict__ pooled, const float* __restrict__ Wout,
                             const float* __restrict__ bout, float* __restrict__ out) {
    int g = blockIdx.x;    // 64
    int o = threadIdx.x;   // 128
    float s = bout[o];
#pragma unroll 4
    for (int k = 0; k < TOTLAT; ++k)
        s += pooled[g * TOTLAT + k] * Wout[k * OUTDIM + o];
    out[g * OUTDIM + o] = fmaxf(s, 0.0f);
}

extern "C" void kernel_launch(void* const* d_in, const int* in_sizes, int n_in,
                              void* d_out, int out_size, void* d_ws, size_t ws_size,
                              hipStream_t stream) {
    const float* node_feat = (const float*)d_in[0];
    const int*   src       = (const int*)d_in[1];
    const int*   dst       = (const int*)d_in[2];
    const int*   graph_ids = (const int*)d_in[3];
    const float* W0 = (const float*)d_in[5];
    const float* b0 = (const float*)d_in[6];
    const float* W1 = (const float*)d_in[7];
    const float* b1 = (const float*)d_in[8];
    const float* W2 = (const float*)d_in[9];
    const float* b2 = (const float*)d_in[10];
    const float* W3 = (const float*)d_in[11];
    const float* b3 = (const float*)d_in[12];
    const float* Wout = (const float*)d_in[13];
    const float* bout = (const float*)d_in[14];
    float* out = (float*)d_out;

    const int N = in_sizes[0] / NFEAT;   // 100000
    const int E = in_sizes[1];           // 3200000
    const int nbuck = (N + NPB - 1) >> BSHIFT;   // 196

    char* ws = (char*)d_ws;
    size_t off = 0;
    auto carve = [&](size_t bytes) -> void* {
        void* p = ws + off;
        off = (off + bytes + 255) & ~(size_t)255;
        return p;
    };
    int*   bucket_cnt    = (int*)carve((size_t)MAXBUCK * 4);
    int*   bucket_start  = (int*)carve((size_t)(MAXBUCK + 1) * 4);
    int*   bucket_cursor = (int*)carve((size_t)MAXBUCK * 4);
    int*   row_ptr       = (int*)carve((size_t)(N + 1) * 4);
    int*   col_idx       = (int*)carve((size_t)(E + 32) * 4);  // +32 slack for chunked over-read
    float* inv_deg       = (float*)carve((size_t)N * 4);
    float* hA            = (float*)carve((size_t)N * NFEAT * 4);
    float* hB            = (float*)carve((size_t)N * NFEAT * 4);
    float* y             = (float*)carve((size_t)N * 4);
    float* pooled        = (float*)carve((size_t)NGRAPH * TOTLAT * 4);
    // pairs (E*8B = 25.6MB) aliases hA+hB (dead before layer 0 writes hA)
    int2*  pairs         = (int2*)hA;

    hipMemsetAsync(bucket_cnt, 0, (size_t)MAXBUCK * 4, stream);
    hipMemsetAsync(pooled, 0, (size_t)NGRAPH * TOTLAT * 4, stream);

    const int nchunks = (E + CH - 1) / CH;
    hist_kernel<<<nchunks, 256, 0, stream>>>(dst, bucket_cnt, E, nbuck);
    bucket_scan_kernel<<<1, MAXBUCK, 0, stream>>>(bucket_cnt, bucket_start, bucket_cursor,
                                                  row_ptr, N, E, nbuck);
    part_kernel<<<nchunks, 256, 0, stream>>>(src, dst, bucket_cursor, pairs, E, nbuck);
    csr_kernel<<<nbuck, NPB, 0, stream>>>(pairs, bucket_start, row_ptr, col_idx, inv_deg, N);

    const int lblocks = (N * 8 + 255) / 256;
    // layer 0: agg(node_feat)->hA; mlp in-place hA -> h0
    agg_kernel<<<lblocks, 256, 0, stream>>>(node_feat, hA, row_ptr, col_idx, N);
    mlp_kernel<false><<<lblocks, 256, 0, stream>>>(hA, W0, b0, inv_deg, graph_ids,
                                                   pooled, 0, nullptr, nullptr, N);
    // layer 1: agg(hA)->hB; mlp in-place hB -> h1
    agg_kernel<<<lblocks, 256, 0, stream>>>(hA, hB, row_ptr, col_idx, N);
    mlp_kernel<false><<<lblocks, 256, 0, stream>>>(hB, W1, b1, inv_deg, graph_ids,
                                                   pooled, 32, nullptr, nullptr, N);
    // layer 2: agg(hB)->hA; mlp emits y = h2@W3 (h2 never written)
    agg_kernel<<<lblocks, 256, 0, stream>>>(hB, hA, row_ptr, col_idx, N);
    mlp_kernel<true><<<lblocks, 256, 0, stream>>>(hA, W2, b2, inv_deg, graph_ids,
                                                  pooled, 64, W3, y, N);
    // layer 3: scalar gather over y
    agg3_kernel<<<(N + 255) / 256, 256, 0, stream>>>(y, b3, row_ptr, col_idx, inv_deg,
                                                     graph_ids, pooled, N);

    final_kernel<<<NGRAPH, OUTDIM, 0, stream>>>(pooled, Wout, bout, out);
}

// Round 13
// 520.494 us; speedup vs baseline: 2.6743x; 1.1231x over previous
//
#include <hip/hip_runtime.h>
#include <hip/hip_bf16.h>

// Graph net: 4x (agg = A@h + h; h = tanh((agg@W + b)/deg1)); concat -> graph sum-pool -> relu(linear)
// N=100000, E=3200000, G=64, feats 32, latent [32,32,32,1], out 128.
//
// R13 == R11 resubmit (R11/R12 hit infra failures, never measured).
// R11: kill pooled-atomic contention (R10 evidence: mlp_kernel 72us @ 366GB/s,
// VALUBusy 7%, occ 15.7% despite VGPR headroom -> waves stalled on 400K
// device-scope atomics to 128 hot lines bouncing across 8 XCD L2s).
// (1) re-fuse MLP into gather with LDS-staged acc (register-light epilogue,
//     launch_bounds(256,8) keeps agg's 32-VGPR/63%-occupancy regime);
// (2) pooling moved to a dedicated pass over materialized h0/h1/h2/z:
//     64 graphs x 4 quarter-blocks, binary-searched ranges, 1 atomic/(block,col).

#define NFEAT 32
#define TOTLAT 97
#define NGRAPH 64
#define OUTDIM 128
#define BSHIFT 9            // 512 nodes per bucket
#define NPB 512
#define MAXBUCK 256
#define CH 8192

__device__ __forceinline__ float ftanh(float x) {
    x = fminf(fmaxf(x, -15.0f), 15.0f);
    float t = __expf(2.0f * x);
    return (t - 1.0f) / (t + 1.0f);
}

// ---------------- CSR build (unchanged) ----------------
__global__ __launch_bounds__(256) void hist_kernel(const int* __restrict__ dst,
                                                   int* __restrict__ bucket_cnt,
                                                   int E, int nbuck) {
    __shared__ int h[MAXBUCK];
    for (int i = threadIdx.x; i < nbuck; i += blockDim.x) h[i] = 0;
    __syncthreads();
    int e0 = blockIdx.x * CH, e1 = min(e0 + CH, E);
    const int4* d4 = (const int4*)dst;
    int k0 = e0 >> 2, nk = (e1 - e0) >> 2;
    for (int k = k0 + threadIdx.x; k < k0 + nk; k += blockDim.x) {
        int4 v = d4[k];
        atomicAdd(&h[v.x >> BSHIFT], 1);
        atomicAdd(&h[v.y >> BSHIFT], 1);
        atomicAdd(&h[v.z >> BSHIFT], 1);
        atomicAdd(&h[v.w >> BSHIFT], 1);
    }
    for (int e = e0 + (nk << 2) + threadIdx.x; e < e1; e += blockDim.x)
        atomicAdd(&h[dst[e] >> BSHIFT], 1);
    __syncthreads();
    for (int i = threadIdx.x; i < nbuck; i += blockDim.x)
        if (h[i]) atomicAdd(&bucket_cnt[i], h[i]);
}

__global__ void bucket_scan_kernel(const int* __restrict__ bucket_cnt,
                                   int* __restrict__ bucket_start,
                                   int* __restrict__ bucket_cursor,
                                   int* __restrict__ row_ptr,
                                   int N, int E, int nbuck) {
    __shared__ int s[MAXBUCK];
    int i = threadIdx.x;
    int v = (i < nbuck) ? bucket_cnt[i] : 0;
    s[i] = v;
    __syncthreads();
    for (int d = 1; d < MAXBUCK; d <<= 1) {
        int t = (i >= d) ? s[i - d] : 0;
        __syncthreads();
        if (i >= d) s[i] += t;
        __syncthreads();
    }
    if (i < nbuck) {
        int excl = s[i] - v;
        bucket_start[i] = excl;
        bucket_cursor[i] = excl;
    }
    if (i == 0) { bucket_start[nbuck] = E; row_ptr[N] = E; }
}

__global__ __launch_bounds__(256) void part_kernel(const int* __restrict__ src,
                                                   const int* __restrict__ dst,
                                                   int* __restrict__ bucket_cursor,
                                                   int2* __restrict__ pairs,
                                                   int E, int nbuck) {
    __shared__ int h[MAXBUCK];
    __shared__ int gb[MAXBUCK];
    for (int i = threadIdx.x; i < nbuck; i += blockDim.x) h[i] = 0;
    __syncthreads();
    int e0 = blockIdx.x * CH, e1 = min(e0 + CH, E);
    const int4* d4 = (const int4*)dst;
    const int4* s4 = (const int4*)src;
    int k0 = e0 >> 2, nk = (e1 - e0) >> 2;
    for (int k = k0 + threadIdx.x; k < k0 + nk; k += blockDim.x) {
        int4 v = d4[k];
        atomicAdd(&h[v.x >> BSHIFT], 1);
        atomicAdd(&h[v.y >> BSHIFT], 1);
        atomicAdd(&h[v.z >> BSHIFT], 1);
        atomicAdd(&h[v.w >> BSHIFT], 1);
    }
    for (int e = e0 + (nk << 2) + threadIdx.x; e < e1; e += blockDim.x)
        atomicAdd(&h[dst[e] >> BSHIFT], 1);
    __syncthreads();
    for (int i = threadIdx.x; i < nbuck; i += blockDim.x) {
        int c = h[i];
        gb[i] = c ? atomicAdd(&bucket_cursor[i], c) : 0;
        h[i] = 0;
    }
    __syncthreads();
    for (int k = k0 + threadIdx.x; k < k0 + nk; k += blockDim.x) {
        int4 d = d4[k];
        int4 s = s4[k];
        int b, r;
        b = d.x >> BSHIFT; r = atomicAdd(&h[b], 1); pairs[gb[b] + r] = make_int2(s.x, d.x);
        b = d.y >> BSHIFT; r = atomicAdd(&h[b], 1); pairs[gb[b] + r] = make_int2(s.y, d.y);
        b = d.z >> BSHIFT; r = atomicAdd(&h[b], 1); pairs[gb[b] + r] = make_int2(s.z, d.z);
        b = d.w >> BSHIFT; r = atomicAdd(&h[b], 1); pairs[gb[b] + r] = make_int2(s.w, d.w);
    }
    for (int e = e0 + (nk << 2) + threadIdx.x; e < e1; e += blockDim.x) {
        int dv = dst[e];
        int b = dv >> BSHIFT;
        int r = atomicAdd(&h[b], 1);
        pairs[gb[b] + r] = make_int2(src[e], dv);
    }
}

__global__ __launch_bounds__(NPB) void csr_kernel(const int2* __restrict__ pairs,
                                                  const int* __restrict__ bucket_start,
                                                  int* __restrict__ row_ptr,
                                                  int* __restrict__ col_idx,
                                                  float* __restrict__ inv_deg, int N) {
    __shared__ int deg[NPB];
    __shared__ int scn[NPB];
    int b = blockIdx.x;
    int n0 = b << BSHIFT;
    int tid = threadIdx.x;
    deg[tid] = 0;
    __syncthreads();
    int e0 = bucket_start[b], e1 = bucket_start[b + 1];
    for (int e = e0 + tid; e < e1; e += NPB) {
        int2 p = pairs[e];
        atomicAdd(&deg[p.y - n0], 1);
    }
    __syncthreads();
    int v = deg[tid];
    scn[tid] = v;
    __syncthreads();
    for (int d = 1; d < NPB; d <<= 1) {
        int t = (tid >= d) ? scn[tid - d] : 0;
        __syncthreads();
        if (tid >= d) scn[tid] += t;
        __syncthreads();
    }
    int excl = scn[tid] - v;
    int n = n0 + tid;
    if (n < N) {
        row_ptr[n] = e0 + excl;
        inv_deg[n] = 1.0f / ((float)v + 1.0f);
    }
    deg[tid] = excl;
    __syncthreads();
    for (int e = e0 + tid; e < e1; e += NPB) {
        int2 p = pairs[e];
        int r = atomicAdd(&deg[p.y - n0], 1);
        col_idx[e0 + r] = p.x;
    }
}

// ---------------- fused layer: gather + MLP (+y), NO pooling atomics ----------------
// 8 lanes/node, float4/lane; 32-edge chunks, clamp-to-self padding.
// MLP epilogue: acc staged in LDS (same-wave, no barrier), W via L1.
template <bool WRITE_Y>
__global__ __launch_bounds__(256, 8) void layer_fused(
    const float* __restrict__ h_in, float* __restrict__ h_out,
    const float* __restrict__ W, const float* __restrict__ bvec,
    const int* __restrict__ row_ptr, const int* __restrict__ col_idx,
    const float* __restrict__ inv_deg,
    const float* __restrict__ W3, float* __restrict__ y, int N)
{
    __shared__ float accs[32][33];   // 32 nodes/block, pad 33 (<=2-way conflicts)
    const int t = blockIdx.x * blockDim.x + threadIdx.x;
    int n = t >> 3;
    const int l8 = t & 7;
    const bool valid = n < N;
    if (!valid) n = N - 1;

    const float4* __restrict__ h4 = (const float4*)h_in;

    int beg = row_ptr[n];
    int end = row_ptr[n + 1];
    int len = end - beg;
    float4 self = h4[(size_t)n * 8 + l8];
    float4 acc = self;

    for (int e = beg; e < end; e += 32) {
        int base = e + l8 * 4;
        int my0 = __builtin_nontemporal_load(&col_idx[base + 0]);
        int my1 = __builtin_nontemporal_load(&col_idx[base + 1]);
        int my2 = __builtin_nontemporal_load(&col_idx[base + 2]);
        int my3 = __builtin_nontemporal_load(&col_idx[base + 3]);
        int rem = end - e;
#pragma unroll
        for (int sl = 0; sl < 8; ++sl) {
            int i0 = __shfl(my0, sl, 8);
            int i1 = __shfl(my1, sl, 8);
            int i2 = __shfl(my2, sl, 8);
            int i3 = __shfl(my3, sl, 8);
            int j = sl * 4;
            i0 = (j + 0 < rem) ? i0 : n;
            i1 = (j + 1 < rem) ? i1 : n;
            i2 = (j + 2 < rem) ? i2 : n;
            i3 = (j + 3 < rem) ? i3 : n;
            float4 v0 = h4[(size_t)i0 * 8 + l8];
            float4 v1 = h4[(size_t)i1 * 8 + l8];
            float4 v2 = h4[(size_t)i2 * 8 + l8];
            float4 v3 = h4[(size_t)i3 * 8 + l8];
            acc.x += v0.x + v1.x + v2.x + v3.x;
            acc.y += v0.y + v1.y + v2.y + v3.y;
            acc.z += v0.z + v1.z + v2.z + v3.z;
            acc.w += v0.w + v1.w + v2.w + v3.w;
        }
    }
    float fk = (float)(((len + 31) & ~31) - len);
    acc.x -= fk * self.x; acc.y -= fk * self.y;
    acc.z -= fk * self.z; acc.w -= fk * self.w;

    // ---- MLP epilogue (register-light; same-wave LDS, no barrier needed) ----
    const int gl = threadIdx.x >> 3;
    const int f0 = l8 * 4;
    accs[gl][f0 + 0] = acc.x;
    accs[gl][f0 + 1] = acc.y;
    accs[gl][f0 + 2] = acc.z;
    accs[gl][f0 + 3] = acc.w;

    float4 o = *(const float4*)&bvec[f0];
#pragma unroll 8
    for (int k = 0; k < NFEAT; ++k) {
        float a = accs[gl][k];                       // LDS broadcast in 8-lane group
        float4 w = *(const float4*)&W[k * NFEAT + f0];  // 4KB, L1-hot
        o.x += a * w.x; o.y += a * w.y; o.z += a * w.z; o.w += a * w.w;
    }
    float ideg = inv_deg[n];
    float4 v;
    v.x = ftanh(o.x * ideg);
    v.y = ftanh(o.y * ideg);
    v.z = ftanh(o.z * ideg);
    v.w = ftanh(o.w * ideg);

    if (valid) {
        *(float4*)&h_out[(size_t)n * NFEAT + f0] = v;
        if (WRITE_Y) {
            float4 wv = *(const float4*)&W3[f0];
            float p = v.x * wv.x + v.y * wv.y + v.z * wv.z + v.w * wv.w;
            p += __shfl_xor(p, 1);
            p += __shfl_xor(p, 2);
            p += __shfl_xor(p, 4);
            if (l8 == 0) y[n] = p;
        }
    }
}

// ---------------- layer 3: scalar gather over y -> z (no atomics) ----------------
__global__ __launch_bounds__(256) void agg3_kernel(
    const float* __restrict__ y, const float* __restrict__ b3,
    const int* __restrict__ row_ptr, const int* __restrict__ col_idx,
    const float* __restrict__ inv_deg, float* __restrict__ z, int N)
{
    int n = blockIdx.x * blockDim.x + threadIdx.x;
    if (n >= N) return;

    int beg = row_ptr[n];
    int end = row_ptr[n + 1];
    float s = y[n];
    int e = beg;
    for (; e + 8 <= end; e += 8) {
        float a0 = y[col_idx[e + 0]];
        float a1 = y[col_idx[e + 1]];
        float a2 = y[col_idx[e + 2]];
        float a3 = y[col_idx[e + 3]];
        float a4 = y[col_idx[e + 4]];
        float a5 = y[col_idx[e + 5]];
        float a6 = y[col_idx[e + 6]];
        float a7 = y[col_idx[e + 7]];
        s += ((a0 + a1) + (a2 + a3)) + ((a4 + a5) + (a6 + a7));
    }
    for (; e < end; ++e)
        s += y[col_idx[e]];

    z[n] = ftanh((s + b3[0]) * inv_deg[n]);
}

// ---------------- pooling: 64 graphs x 4 quarters, binary-searched ranges ----------------
__global__ __launch_bounds__(128) void pool_kernel(
    const float* __restrict__ h0, const float* __restrict__ h1,
    const float* __restrict__ h2, const float* __restrict__ z,
    const int* __restrict__ graph_ids, float* __restrict__ pooled, int N)
{
    __shared__ int sb[2];
    int g = blockIdx.x >> 2, q = blockIdx.x & 3;
    if (threadIdx.x == 0) {
        int lo = 0, hi = N;
        while (lo < hi) { int m = (lo + hi) >> 1; if (graph_ids[m] < g) lo = m + 1; else hi = m; }
        sb[0] = lo;
        lo = 0; hi = N;
        while (lo < hi) { int m = (lo + hi) >> 1; if (graph_ids[m] < g + 1) lo = m + 1; else hi = m; }
        sb[1] = lo;
    }
    __syncthreads();
    int s = sb[0], e = sb[1];
    int per = (e - s + 3) >> 2;
    int ns = s + q * per;
    int ne = min(ns + per, e);
    int c = threadIdx.x;
    if (c >= TOTLAT || ns >= ne) return;

    float sum = 0.0f;
    if (c < 32) {
        const float* p = h0 + c;
#pragma unroll 4
        for (int n = ns; n < ne; ++n) sum += p[(size_t)n * NFEAT];
    } else if (c < 64) {
        const float* p = h1 + (c - 32);
#pragma unroll 4
        for (int n = ns; n < ne; ++n) sum += p[(size_t)n * NFEAT];
    } else if (c < 96) {
        const float* p = h2 + (c - 64);
#pragma unroll 4
        for (int n = ns; n < ne; ++n) sum += p[(size_t)n * NFEAT];
    } else {
#pragma unroll 4
        for (int n = ns; n < ne; ++n) sum += z[n];
    }
    atomicAdd(&pooled[g * TOTLAT + c], sum);   // 4-way contention only
}

__global__ void final_kernel(const float* __restrict__ pooled, const float* __restrict__ Wout,
                             const float* __restrict__ bout, float* __restrict__ out) {
    int g = blockIdx.x;    // 64
    int o = threadIdx.x;   // 128
    float s = bout[o];
#pragma unroll 4
    for (int k = 0; k < TOTLAT; ++k)
        s += pooled[g * TOTLAT + k] * Wout[k * OUTDIM + o];
    out[g * OUTDIM + o] = fmaxf(s, 0.0f);
}

extern "C" void kernel_launch(void* const* d_in, const int* in_sizes, int n_in,
                              void* d_out, int out_size, void* d_ws, size_t ws_size,
                              hipStream_t stream) {
    const float* node_feat = (const float*)d_in[0];
    const int*   src       = (const int*)d_in[1];
    const int*   dst       = (const int*)d_in[2];
    const int*   graph_ids = (const int*)d_in[3];
    const float* W0 = (const float*)d_in[5];
    const float* b0 = (const float*)d_in[6];
    const float* W1 = (const float*)d_in[7];
    const float* b1 = (const float*)d_in[8];
    const float* W2 = (const float*)d_in[9];
    const float* b2 = (const float*)d_in[10];
    const float* W3 = (const float*)d_in[11];
    const float* b3 = (const float*)d_in[12];
    const float* Wout = (const float*)d_in[13];
    const float* bout = (const float*)d_in[14];
    float* out = (float*)d_out;

    const int N = in_sizes[0] / NFEAT;   // 100000
    const int E = in_sizes[1];           // 3200000
    const int nbuck = (N + NPB - 1) >> BSHIFT;   // 196

    char* ws = (char*)d_ws;
    size_t off = 0;
    auto carve = [&](size_t bytes) -> void* {
        void* p = ws + off;
        off = (off + bytes + 255) & ~(size_t)255;
        return p;
    };
    int*   bucket_cnt    = (int*)carve((size_t)MAXBUCK * 4);
    int*   bucket_start  = (int*)carve((size_t)(MAXBUCK + 1) * 4);
    int*   bucket_cursor = (int*)carve((size_t)MAXBUCK * 4);
    int*   row_ptr       = (int*)carve((size_t)(N + 1) * 4);
    int*   col_idx       = (int*)carve((size_t)(E + 32) * 4);  // +32 slack for chunked over-read
    float* inv_deg       = (float*)carve((size_t)N * 4);
    float* hA            = (float*)carve((size_t)N * NFEAT * 4);
    float* hB            = (float*)carve((size_t)N * NFEAT * 4);
    float* hC            = (float*)carve((size_t)N * NFEAT * 4);
    float* y             = (float*)carve((size_t)N * 4);
    float* z             = (float*)carve((size_t)N * 4);
    float* pooled        = (float*)carve((size_t)NGRAPH * TOTLAT * 4);
    // pairs (E*8B = 25.6MB) aliases hA+hB (dead before layer 0 writes hA)
    int2*  pairs         = (int2*)hA;

    hipMemsetAsync(bucket_cnt, 0, (size_t)MAXBUCK * 4, stream);
    hipMemsetAsync(pooled, 0, (size_t)NGRAPH * TOTLAT * 4, stream);

    const int nchunks = (E + CH - 1) / CH;
    hist_kernel<<<nchunks, 256, 0, stream>>>(dst, bucket_cnt, E, nbuck);
    bucket_scan_kernel<<<1, MAXBUCK, 0, stream>>>(bucket_cnt, bucket_start, bucket_cursor,
                                                  row_ptr, N, E, nbuck);
    part_kernel<<<nchunks, 256, 0, stream>>>(src, dst, bucket_cursor, pairs, E, nbuck);
    csr_kernel<<<nbuck, NPB, 0, stream>>>(pairs, bucket_start, row_ptr, col_idx, inv_deg, N);

    const int lblocks = (N * 8 + 255) / 256;
    layer_fused<false><<<lblocks, 256, 0, stream>>>(node_feat, hA, W0, b0, row_ptr, col_idx,
                                                    inv_deg, nullptr, nullptr, N);
    layer_fused<false><<<lblocks, 256, 0, stream>>>(hA, hB, W1, b1, row_ptr, col_idx,
                                                    inv_deg, nullptr, nullptr, N);
    layer_fused<true><<<lblocks, 256, 0, stream>>>(hB, hC, W2, b2, row_ptr, col_idx,
                                                   inv_deg, W3, y, N);
    agg3_kernel<<<(N + 255) / 256, 256, 0, stream>>>(y, b3, row_ptr, col_idx, inv_deg, z, N);

    pool_kernel<<<NGRAPH * 4, 128, 0, stream>>>(hA, hB, hC, z, graph_ids, pooled, N);
    final_kernel<<<NGRAPH, OUTDIM, 0, stream>>>(pooled, Wout, bout, out);
}